// Round 1
// baseline (2247.718 us; speedup 1.0000x reference)
//
#include <hip/hip_runtime.h>
#include <hip/hip_bf16.h>

#define NN 100000
#define EE 1600000
#define GG 64
#define HH 128
#define LL 3
#define BN_EPS 1e-5f

// ---------------- CSR build ----------------
__global__ void deg_kernel(const int* __restrict__ dst, int* __restrict__ deg) {
    int e = blockIdx.x * 256 + threadIdx.x;
    if (e < EE) atomicAdd(&deg[dst[e]], 1);
}

__global__ void scan_block_kernel(const int* __restrict__ deg, int* __restrict__ rowstart,
                                  int* __restrict__ partials, int n) {
    __shared__ int s[1024];
    int tid = threadIdx.x;
    int i = blockIdx.x * 1024 + tid;
    int v = (i < n) ? deg[i] : 0;
    s[tid] = v;
    __syncthreads();
    for (int off = 1; off < 1024; off <<= 1) {
        int t = (tid >= off) ? s[tid - off] : 0;
        __syncthreads();
        s[tid] += t;
        __syncthreads();
    }
    if (i < n) rowstart[i] = s[tid] - v;   // exclusive
    if (tid == 1023) partials[blockIdx.x] = s[1023];
}

__global__ void scan_partials_kernel(int* partials, int nb) {
    if (blockIdx.x == 0 && threadIdx.x == 0) {
        int acc = 0;
        for (int i = 0; i < nb; ++i) { int v = partials[i]; partials[i] = acc; acc += v; }
    }
}

__global__ void add_offsets_kernel(int* __restrict__ rowstart, const int* __restrict__ partials,
                                   int n, int total) {
    int i = blockIdx.x * 256 + threadIdx.x;
    if (i < n) rowstart[i] += partials[i >> 10];
    if (i == n) rowstart[n] = total;
}

__global__ void fill_col_kernel(const int* __restrict__ src, const int* __restrict__ dst,
                                const int* __restrict__ rowstart, int* __restrict__ cursor,
                                int* __restrict__ col) {
    int e = blockIdx.x * 256 + threadIdx.x;
    if (e < EE) {
        int d = dst[e];
        int pos = atomicAdd(&cursor[d], 1);
        col[rowstart[d] + pos] = src[e];
    }
}

// ---------------- graph counts ----------------
__global__ void counts_kernel(const int* __restrict__ batch, float* __restrict__ cnt, int n) {
    __shared__ int h[GG];
    int tid = threadIdx.x;
    if (tid < GG) h[tid] = 0;
    __syncthreads();
    int i = blockIdx.x * 256 + tid;
    if (i < n) atomicAdd(&h[batch[i]], 1);
    __syncthreads();
    if (tid < GG && h[tid]) atomicAdd(&cnt[tid], (float)h[tid]);
}

// ---------------- gather: out[i] = affine-applied (h[i] + sum_{j->i} h[j]) ----------------
// affine from BN of previous layer: val = a*h + b, factored: a*(sum raw) + b*(deg+1)
__global__ void gather_kernel(const float* __restrict__ h, const int* __restrict__ rowstart,
                              const int* __restrict__ col, const float* __restrict__ cA,
                              const float* __restrict__ cB, float* __restrict__ out, int n) {
    int gw = (blockIdx.x * blockDim.x + threadIdx.x) >> 6;   // one wave per node
    int lane = threadIdx.x & 63;
    if (gw >= n) return;
    const float2* h2 = (const float2*)h;
    float2 a = ((const float2*)cA)[lane];
    float2 b = ((const float2*)cB)[lane];
    float2 acc = h2[(size_t)gw * 64 + lane];
    int beg = rowstart[gw], end = rowstart[gw + 1];
    float degp1 = (float)(end - beg + 1);
    for (int e = beg; e < end; ++e) {
        int j = col[e];
        float2 u = h2[(size_t)j * 64 + lane];
        acc.x += u.x; acc.y += u.y;
    }
    float2 o;
    o.x = a.x * acc.x + b.x * degp1;
    o.y = a.y * acc.y + b.y * degp1;
    ((float2*)out)[(size_t)gw * 64 + lane] = o;
}

// ---------------- GEMM: Y = relu(X @ W + bias), optional BN stats ----------------
// X [n,128], W [128,128] row-major, tile 64 rows x 128 cols, K-chunks of 32.
template <bool STATS>
__global__ __launch_bounds__(256) void mlp_gemm_kernel(
    const float* __restrict__ X, const float* __restrict__ W, const float* __restrict__ bias,
    float* __restrict__ Y, float* __restrict__ stats, int n) {
    __shared__ float As[32][68];    // [k][row], padded (272B stride, 16B aligned)
    __shared__ float Bs[32][128];   // [k][col]
    int tid = threadIdx.x;
    int tx = tid & 15;    // col group: cols tx*8 .. +7
    int ty = tid >> 4;    // row group: rows ty*4 .. +3
    int row0 = blockIdx.x * 64;
    float acc[4][8];
#pragma unroll
    for (int r = 0; r < 4; ++r)
#pragma unroll
        for (int c = 0; c < 8; ++c) acc[r][c] = 0.f;

    for (int k0 = 0; k0 < 128; k0 += 32) {
#pragma unroll
        for (int it = 0; it < 2; ++it) {
            int li = it * 256 + tid;       // 0..511
            int r = li >> 3;               // 0..63
            int cg = li & 7;               // float4 group
            int grow = row0 + r;
            float4 v = make_float4(0.f, 0.f, 0.f, 0.f);
            if (grow < n) v = *(const float4*)(X + (size_t)grow * 128 + k0 + cg * 4);
            As[cg * 4 + 0][r] = v.x;
            As[cg * 4 + 1][r] = v.y;
            As[cg * 4 + 2][r] = v.z;
            As[cg * 4 + 3][r] = v.w;
        }
#pragma unroll
        for (int it = 0; it < 4; ++it) {
            int li = it * 256 + tid;       // 0..1023
            int kr = li >> 5;              // 0..31
            int cg = li & 31;
            *(float4*)(&Bs[kr][cg * 4]) = *(const float4*)(W + (size_t)(k0 + kr) * 128 + cg * 4);
        }
        __syncthreads();
#pragma unroll
        for (int kk = 0; kk < 32; ++kk) {
            float4 a4 = *(const float4*)(&As[kk][ty * 4]);
            float4 b0 = *(const float4*)(&Bs[kk][tx * 8]);
            float4 b1 = *(const float4*)(&Bs[kk][tx * 8 + 4]);
            float a[4] = {a4.x, a4.y, a4.z, a4.w};
            float b[8] = {b0.x, b0.y, b0.z, b0.w, b1.x, b1.y, b1.z, b1.w};
#pragma unroll
            for (int r = 0; r < 4; ++r)
#pragma unroll
                for (int c = 0; c < 8; ++c) acc[r][c] += a[r] * b[c];
        }
        __syncthreads();
    }

    float4 bj0 = *(const float4*)(bias + tx * 8);
    float4 bj1 = *(const float4*)(bias + tx * 8 + 4);
    float bj[8] = {bj0.x, bj0.y, bj0.z, bj0.w, bj1.x, bj1.y, bj1.z, bj1.w};

    float colsum[8], colsq[8];
#pragma unroll
    for (int c = 0; c < 8; ++c) { colsum[c] = 0.f; colsq[c] = 0.f; }

#pragma unroll
    for (int r = 0; r < 4; ++r) {
        int grow = row0 + ty * 4 + r;
        if (grow < n) {
            float v[8];
#pragma unroll
            for (int c = 0; c < 8; ++c) {
                v[c] = fmaxf(acc[r][c] + bj[c], 0.f);
                if (STATS) { colsum[c] += v[c]; colsq[c] += v[c] * v[c]; }
            }
            float4 o0 = make_float4(v[0], v[1], v[2], v[3]);
            float4 o1 = make_float4(v[4], v[5], v[6], v[7]);
            *(float4*)(Y + (size_t)grow * 128 + tx * 8) = o0;
            *(float4*)(Y + (size_t)grow * 128 + tx * 8 + 4) = o1;
        }
    }

    if (STATS) {
        __shared__ float ssum[128], ssq[128];
        if (tid < 128) { ssum[tid] = 0.f; ssq[tid] = 0.f; }
        __syncthreads();
#pragma unroll
        for (int c = 0; c < 8; ++c) {
            atomicAdd(&ssum[tx * 8 + c], colsum[c]);
            atomicAdd(&ssq[tx * 8 + c], colsq[c]);
        }
        __syncthreads();
        if (tid < 128) {
            atomicAdd(&stats[tid], ssum[tid]);
            atomicAdd(&stats[128 + tid], ssq[tid]);
        }
    }
}

// ---------------- BN coefs from stats (and re-zero stats for next layer) ----------------
__global__ void bn_coefs_kernel(float* __restrict__ stats, const float* __restrict__ g,
                                const float* __restrict__ bt, float* __restrict__ cA,
                                float* __restrict__ cB) {
    int c = threadIdx.x;
    float s = stats[c], sq = stats[128 + c];
    float inv_n = 1.0f / (float)NN;
    float mu = s * inv_n;
    float var = sq * inv_n - mu * mu;
    float a = g[c] * rsqrtf(var + BN_EPS);
    cA[c] = a;
    cB[c] = bt[c] - mu * a;
    stats[c] = 0.f;
    stats[128 + c] = 0.f;
}

__global__ void init_coefs_kernel(float* cA, float* cB) {
    int c = threadIdx.x;
    cA[c] = 1.f;
    cB[c] = 0.f;
}

// ---------------- pooling: pool[g][c] += affine(h[i][c]) for batch[i]==g ----------------
#define POOL_CHUNK 128
__global__ void pool_kernel(const float* __restrict__ h, const float* __restrict__ cA,
                            const float* __restrict__ cB, const int* __restrict__ batch,
                            float* __restrict__ pool, int n) {
    int c = threadIdx.x;   // 128 threads
    int i0 = blockIdx.x * POOL_CHUNK;
    if (i0 >= n) return;
    int i1 = min(i0 + POOL_CHUNK, n);
    float a = cA[c], b = cB[c];
    float acc = 0.f;
    int cur = batch[i0];
    for (int i = i0; i < i1; ++i) {
        int g = batch[i];
        if (g != cur) {
            atomicAdd(&pool[cur * 128 + c], acc);
            acc = 0.f;
            cur = g;
        }
        acc += a * h[(size_t)i * 128 + c] + b;
    }
    atomicAdd(&pool[cur * 128 + c], acc);
}

__global__ void finalize_pool_kernel(const float* __restrict__ poolA, const float* __restrict__ poolB,
                                     const float* __restrict__ cnt, float* __restrict__ meanA,
                                     float* __restrict__ meanB) {
    int g = blockIdx.x, c = threadIdx.x;
    float cc = fmaxf(cnt[g], 1.0f);
    meanA[g * 128 + c] = poolA[g * 128 + c] / cc;
    meanB[g * 128 + c] = poolB[g * 128 + c] / cc;
}

// ---------------- bilinear discriminator ----------------
__global__ void disc_kernel(const float* __restrict__ poolX, const float* __restrict__ W,
                            const float* __restrict__ db, float* __restrict__ out) {
    int g = blockIdx.x, e = threadIdx.x;    // 128 threads
    __shared__ float rs[128], rh[128];
    const float* a = poolX + g * 128;
    float t = 0.f;
    for (int d = 0; d < 128; ++d) t += a[d] * W[d * 128 + e];
    int gs = (g == 32) ? 30 : (63 - g);
    rs[e] = t * poolX[g * 128 + e];
    rh[e] = t * poolX[gs * 128 + e];
    __syncthreads();
    for (int s = 64; s > 0; s >>= 1) {
        if (e < s) { rs[e] += rs[e + s]; rh[e] += rh[e + s]; }
        __syncthreads();
    }
    if (e == 0) {
        out[GG * 10 + g] = rs[0] + db[0];
        out[GG * 10 + GG + g] = rh[0] + db[0];
    }
}

// ---------------- classification head ----------------
__global__ void head_kernel(const float* __restrict__ meanA, const float* __restrict__ poolX,
                            const float* __restrict__ w1, const float* __restrict__ b1,
                            const float* __restrict__ w2, const float* __restrict__ b2,
                            float* __restrict__ out) {
    int g = blockIdx.x, j = threadIdx.x;   // 128 threads
    __shared__ float s1[128];
    __shared__ float s2[10];
    __shared__ float lse;
    const float* ma = meanA + g * 128;
    const float* px = poolX + g * 128;
    float acc = b1[j];
    for (int k = 0; k < 128; ++k) acc += ma[k] * w1[k * 128 + j];
    for (int k = 0; k < 128; ++k) acc += px[k] * w1[(128 + k) * 128 + j];
    s1[j] = fmaxf(acc, 0.f);
    __syncthreads();
    if (j < 10) {
        float a = b2[j];
        for (int k = 0; k < 128; ++k) a += s1[k] * w2[k * 10 + j];
        s2[j] = a;
    }
    __syncthreads();
    if (j == 0) {
        float m = s2[0];
        for (int o = 1; o < 10; ++o) m = fmaxf(m, s2[o]);
        float se = 0.f;
        for (int o = 0; o < 10; ++o) se += expf(s2[o] - m);
        lse = m + logf(se);
    }
    __syncthreads();
    if (j < 10) out[g * 10 + j] = s2[j] - lse;
}

extern "C" void kernel_launch(void* const* d_in, const int* in_sizes, int n_in,
                              void* d_out, int out_size, void* d_ws, size_t ws_size,
                              hipStream_t stream) {
    const float* x     = (const float*)d_in[0];
    const int*   ei    = (const int*)d_in[1];
    const int*   batch = (const int*)d_in[2];
    const float* W1a = (const float*)d_in[3];
    const float* b1a = (const float*)d_in[4];
    const float* W2a = (const float*)d_in[5];
    const float* b2a = (const float*)d_in[6];
    const float* ga  = (const float*)d_in[7];
    const float* bta = (const float*)d_in[8];
    const float* W1b = (const float*)d_in[9];
    const float* b1b = (const float*)d_in[10];
    const float* W2b = (const float*)d_in[11];
    const float* b2b = (const float*)d_in[12];
    const float* gb  = (const float*)d_in[13];
    const float* btb = (const float*)d_in[14];
    const float* lin1_w = (const float*)d_in[15];
    const float* lin1_b = (const float*)d_in[16];
    const float* lin2_w = (const float*)d_in[17];
    const float* lin2_b = (const float*)d_in[18];
    const float* disc_w = (const float*)d_in[19];
    const float* disc_b = (const float*)d_in[20];
    float* out = (float*)d_out;

    const int* src = ei;
    const int* dst = ei + EE;

    // ---- workspace layout (256B aligned) ----
    size_t o = 0;
    auto take = [&](size_t b) { size_t p = o; o = (o + b + 255) & ~(size_t)255; return p; };
    const size_t NB = (size_t)NN * 128 * 4;
    uint8_t* w = (uint8_t*)d_ws;
    size_t o_fA = take(NB);            // gather output (X for GEMM1)
    size_t o_fB = take(NB);            // GEMM1 output (hidden)
    size_t o_fC = take(NB);            // GEMM2 output (layer output, raw pre-BN)
    size_t o_col = take((size_t)EE * 4);
    size_t o_rowstart = take((size_t)(NN + 1) * 4);
    size_t o_partials = take(512);
    size_t zero_begin = o;
    size_t o_deg = take((size_t)NN * 4);
    size_t o_cursor = take((size_t)NN * 4);
    size_t o_stats = take(256 * 4);
    size_t o_cnt = take(GG * 4);
    size_t o_poolA = take((size_t)GG * 128 * 4);
    size_t o_poolB = take((size_t)GG * 128 * 4);
    size_t zero_end = o;
    size_t o_cA = take(128 * 4);
    size_t o_cB = take(128 * 4);
    size_t o_meanA = take((size_t)GG * 128 * 4);
    size_t o_meanB = take((size_t)GG * 128 * 4);

    float* fA = (float*)(w + o_fA);
    float* fB = (float*)(w + o_fB);
    float* fC = (float*)(w + o_fC);
    int* col = (int*)(w + o_col);
    int* rowstart = (int*)(w + o_rowstart);
    int* partials = (int*)(w + o_partials);
    int* deg = (int*)(w + o_deg);
    int* cursor = (int*)(w + o_cursor);
    float* stats = (float*)(w + o_stats);
    float* cnt = (float*)(w + o_cnt);
    float* poolA = (float*)(w + o_poolA);
    float* poolB = (float*)(w + o_poolB);
    float* cA = (float*)(w + o_cA);
    float* cB = (float*)(w + o_cB);
    float* meanA = (float*)(w + o_meanA);
    float* meanB = (float*)(w + o_meanB);

    hipMemsetAsync(w + zero_begin, 0, zero_end - zero_begin, stream);

    // ---- CSR build (by dst) ----
    int ebl = (EE + 255) / 256;
    deg_kernel<<<ebl, 256, 0, stream>>>(dst, deg);
    int nScanBlocks = (NN + 1023) / 1024;
    scan_block_kernel<<<nScanBlocks, 1024, 0, stream>>>(deg, rowstart, partials, NN);
    scan_partials_kernel<<<1, 64, 0, stream>>>(partials, nScanBlocks);
    add_offsets_kernel<<<(NN + 1 + 255) / 256, 256, 0, stream>>>(rowstart, partials, NN, EE);
    fill_col_kernel<<<ebl, 256, 0, stream>>>(src, dst, rowstart, cursor, col);
    counts_kernel<<<(NN + 255) / 256, 256, 0, stream>>>(batch, cnt, NN);

    int gatherBlocks = (NN + 3) / 4;         // 4 waves/block, wave per node
    int gemmBlocks = (NN + 63) / 64;

    // ---- two branches ----
    for (int br = 0; br < 2; ++br) {
        const float* W1 = br ? W1b : W1a;
        const float* B1 = br ? b1b : b1a;
        const float* W2 = br ? W2b : W2a;
        const float* B2 = br ? b2b : b2a;
        const float* Gm = br ? gb : ga;
        const float* Bt = br ? btb : bta;
        float* pool = br ? poolB : poolA;

        init_coefs_kernel<<<1, 128, 0, stream>>>(cA, cB);
        const float* hprev = x;
        for (int l = 0; l < LL; ++l) {
            gather_kernel<<<gatherBlocks, 256, 0, stream>>>(hprev, rowstart, col, cA, cB, fA, NN);
            mlp_gemm_kernel<false><<<gemmBlocks, 256, 0, stream>>>(
                fA, W1 + (size_t)l * 128 * 128, B1 + l * 128, fB, nullptr, NN);
            mlp_gemm_kernel<true><<<gemmBlocks, 256, 0, stream>>>(
                fB, W2 + (size_t)l * 128 * 128, B2 + l * 128, fC, stats, NN);
            bn_coefs_kernel<<<1, 128, 0, stream>>>(stats, Gm + l * 128, Bt + l * 128, cA, cB);
            hprev = fC;
        }
        pool_kernel<<<(NN + POOL_CHUNK - 1) / POOL_CHUNK, 128, 0, stream>>>(
            hprev, cA, cB, batch, pool, NN);
    }

    finalize_pool_kernel<<<GG, 128, 0, stream>>>(poolA, poolB, cnt, meanA, meanB);
    disc_kernel<<<GG, 128, 0, stream>>>(meanB, disc_w, disc_b, out);
    head_kernel<<<GG, 128, 0, stream>>>(meanA, meanB, lin1_w, lin1_b, lin2_w, lin2_b, out);
}

// Round 2
// 1096.508 us; speedup vs baseline: 2.0499x; 2.0499x over previous
//
#include <hip/hip_runtime.h>
#include <hip/hip_bf16.h>

#define NN 100000
#define EE 1600000
#define GG 64
#define HH 128
#define LL 3
#define BN_EPS 1e-5f

typedef __attribute__((ext_vector_type(8))) short bf16x8;
typedef __attribute__((ext_vector_type(4))) float f32x4;
typedef unsigned int uint32;
typedef unsigned short ushort16;

__device__ __forceinline__ float bflo(uint32 u) { return __uint_as_float(u << 16); }
__device__ __forceinline__ float bfhi(uint32 u) { return __uint_as_float(u & 0xffff0000u); }
__device__ __forceinline__ unsigned short f2bf(float f) {
    uint32 x = __float_as_uint(f);
    uint32 r = (x + 0x7fffu + ((x >> 16) & 1u)) >> 16;
    return (unsigned short)r;
}
__device__ __forceinline__ float bf2f(unsigned short u) { return __uint_as_float(((uint32)u) << 16); }

// ---------------- CSR build ----------------
__global__ void deg_kernel(const int* __restrict__ dst, int* __restrict__ deg) {
    int e = blockIdx.x * 256 + threadIdx.x;
    if (e < EE) atomicAdd(&deg[dst[e]], 1);
}

__global__ void scan_block_kernel(const int* __restrict__ deg, int* __restrict__ rowstart,
                                  int* __restrict__ partials, int n) {
    __shared__ int s[1024];
    int tid = threadIdx.x;
    int i = blockIdx.x * 1024 + tid;
    int v = (i < n) ? deg[i] : 0;
    s[tid] = v;
    __syncthreads();
    for (int off = 1; off < 1024; off <<= 1) {
        int t = (tid >= off) ? s[tid - off] : 0;
        __syncthreads();
        s[tid] += t;
        __syncthreads();
    }
    if (i < n) rowstart[i] = s[tid] - v;   // exclusive
    if (tid == 1023) partials[blockIdx.x] = s[1023];
}

__global__ void scan_partials_kernel(int* partials, int nb) {
    if (blockIdx.x == 0 && threadIdx.x == 0) {
        int acc = 0;
        for (int i = 0; i < nb; ++i) { int v = partials[i]; partials[i] = acc; acc += v; }
    }
}

__global__ void add_offsets_kernel(int* __restrict__ rowstart, const int* __restrict__ partials,
                                   int n, int total) {
    int i = blockIdx.x * 256 + threadIdx.x;
    if (i < n) rowstart[i] += partials[i >> 10];
    if (i == n) rowstart[n] = total;
}

__global__ void fill_col_kernel(const int* __restrict__ src, const int* __restrict__ dst,
                                const int* __restrict__ rowstart, int* __restrict__ cursor,
                                int* __restrict__ col) {
    int e = blockIdx.x * 256 + threadIdx.x;
    if (e < EE) {
        int d = dst[e];
        int pos = atomicAdd(&cursor[d], 1);
        col[rowstart[d] + pos] = src[e];
    }
}

// ---------------- graph counts ----------------
__global__ void counts_kernel(const int* __restrict__ batch, float* __restrict__ cnt, int n) {
    __shared__ int h[GG];
    int tid = threadIdx.x;
    if (tid < GG) h[tid] = 0;
    __syncthreads();
    int i = blockIdx.x * 256 + tid;
    if (i < n) atomicAdd(&h[batch[i]], 1);
    __syncthreads();
    if (tid < GG && h[tid]) atomicAdd(&cnt[tid], (float)h[tid]);
}

// ---------------- conversions ----------------
__global__ void x_to_bf16_kernel(const float* __restrict__ x, ushort16* __restrict__ xb) {
    int i = blockIdx.x * 256 + threadIdx.x;   // each handles 4 floats
    if (i < NN * 32) {
        float4 v = ((const float4*)x)[i];
        uint2 o;
        o.x = (uint32)f2bf(v.x) | ((uint32)f2bf(v.y) << 16);
        o.y = (uint32)f2bf(v.z) | ((uint32)f2bf(v.w) << 16);
        ((uint2*)xb)[i] = o;
    }
}

// frag-order weights: [br(2)][l(3)][mat(2)][nt(8)][ks(4)][lane(64)][j(8)]
// value = W[k = ks*32 + (lane>>4)*8 + j][n = nt*16 + (lane&15)]
__global__ void convert_w_kernel(const float* __restrict__ W1a, const float* __restrict__ W2a,
                                 const float* __restrict__ W1b, const float* __restrict__ W2b,
                                 ushort16* __restrict__ out) {
    int t = blockIdx.x * 256 + threadIdx.x;
    if (t >= 24576) return;
    int lane = t & 63;
    int r = t >> 6;
    int ks = r & 3; r >>= 2;
    int nt = r & 7; r >>= 3;
    int mat = r & 1; r >>= 1;
    int l = r % 3, br = r / 3;
    const float* W = br ? (mat ? W2b : W1b) : (mat ? W2a : W1a);
    const float* Wl = W + (size_t)l * 128 * 128;
    int n0 = nt * 16 + (lane & 15);
    int k0 = ks * 32 + (lane >> 4) * 8;
    unsigned short tmp[8];
#pragma unroll
    for (int j = 0; j < 8; ++j) tmp[j] = f2bf(Wl[(size_t)(k0 + j) * 128 + n0]);
    size_t seq = (size_t)(br * 3 + l) * 2 + mat;
    size_t off = (((seq * 8 + nt) * 4 + ks) * 64 + (size_t)lane) * 8;
    *(uint4*)((unsigned short*)out + off) = *(const uint4*)tmp;
}

// ---------------- gather (bf16): out[i] = bf16( a*(h[i]+sum_j h[j]) + b*(deg+1) ) ----------------
__global__ void gather_kernel(const ushort16* __restrict__ h, const int* __restrict__ rowstart,
                              const int* __restrict__ col, const float* __restrict__ cA,
                              const float* __restrict__ cB, ushort16* __restrict__ out, int n) {
    int gw = (blockIdx.x * blockDim.x + threadIdx.x) >> 6;   // one wave per node
    int lane = threadIdx.x & 63;
    if (gw >= n) return;
    const uint32* h32 = (const uint32*)h;
    float2 a = ((const float2*)cA)[lane];
    float2 b = ((const float2*)cB)[lane];
    uint32 self = h32[(size_t)gw * 64 + lane];
    float a0x = bflo(self), a0y = bfhi(self);
    float a1x = 0.f, a1y = 0.f;
    int beg = rowstart[gw], end = rowstart[gw + 1];
    float degp1 = (float)(end - beg + 1);
    int e = beg;
    for (; e + 4 <= end; e += 4) {
        int j0 = col[e], j1 = col[e + 1], j2 = col[e + 2], j3 = col[e + 3];
        uint32 u0 = h32[(size_t)j0 * 64 + lane];
        uint32 u1 = h32[(size_t)j1 * 64 + lane];
        uint32 u2 = h32[(size_t)j2 * 64 + lane];
        uint32 u3 = h32[(size_t)j3 * 64 + lane];
        a0x += bflo(u0); a0y += bfhi(u0);
        a1x += bflo(u1); a1y += bfhi(u1);
        a0x += bflo(u2); a0y += bfhi(u2);
        a1x += bflo(u3); a1y += bfhi(u3);
    }
    for (; e < end; ++e) {
        uint32 u = h32[(size_t)col[e] * 64 + lane];
        a0x += bflo(u); a0y += bfhi(u);
    }
    float ox = a.x * (a0x + a1x) + b.x * degp1;
    float oy = a.y * (a0y + a1y) + b.y * degp1;
    uint32 o = (uint32)f2bf(ox) | ((uint32)f2bf(oy) << 16);
    ((uint32*)out)[(size_t)gw * 64 + lane] = o;
}

// ---------------- fused MLP: Y = relu(relu(X@W1+b1)@W2+b2), BN stats on Y ----------------
#define MAT_STRIDE 16384   // ushort elements per frag-ordered matrix

__global__ __launch_bounds__(256, 2) void mlp_fused_kernel(
    const ushort16* __restrict__ X, const ushort16* __restrict__ Wf,
    const float* __restrict__ b1, const float* __restrict__ b2,
    ushort16* __restrict__ Y, float* __restrict__ stats, int n) {
    __shared__ unsigned short w1s[MAT_STRIDE];     // 32 KB
    __shared__ unsigned short hs[4][16][136];      // 17.4 KB, per-wave private
    __shared__ float ssum[128], ssq[128];

    int tid = threadIdx.x;
    int wv = tid >> 6, lane = tid & 63;
    int quad = lane >> 4, l16 = lane & 15;

    // stage W1 frags to LDS
    {
        const uint4* srcp = (const uint4*)Wf;      // 2048 uint4
        uint4* dstp = (uint4*)w1s;
        for (int i = tid; i < 2048; i += 256) dstp[i] = srcp[i];
    }
    if (tid < 128) { ssum[tid] = 0.f; ssq[tid] = 0.f; }
    __syncthreads();

    // W2 frags in registers
    bf16x8 w2f[8][4];
    {
        const bf16x8* w2g = (const bf16x8*)((const unsigned short*)Wf + MAT_STRIDE);
#pragma unroll
        for (int nt = 0; nt < 8; ++nt)
#pragma unroll
            for (int ks = 0; ks < 4; ++ks) w2f[nt][ks] = w2g[(nt * 4 + ks) * 64 + lane];
    }

    int row0 = blockIdx.x * 64 + wv * 16;

    // A frags from X (lane -> row l16, k chunk quad*8)
    bf16x8 aF[4];
    {
        int r = row0 + l16;
        if (r >= n) r = n - 1;
        const bf16x8* xrow = (const bf16x8*)((const unsigned short*)X + (size_t)r * 128);
#pragma unroll
        for (int ks = 0; ks < 4; ++ks) aF[ks] = xrow[ks * 4 + quad];
    }

    // GEMM1
    f32x4 acc1[8];
#pragma unroll
    for (int nt = 0; nt < 8; ++nt) {
        f32x4 c = {0.f, 0.f, 0.f, 0.f};
#pragma unroll
        for (int ks = 0; ks < 4; ++ks) {
            bf16x8 bfrag = *(const bf16x8*)(&w1s[((nt * 4 + ks) * 64 + lane) * 8]);
            c = __builtin_amdgcn_mfma_f32_16x16x32_bf16(aF[ks], bfrag, c, 0, 0, 0);
        }
        acc1[nt] = c;
    }

    // H = relu(acc1 + b1) -> hs (C-layout scatter)
#pragma unroll
    for (int nt = 0; nt < 8; ++nt) {
        int c0 = nt * 16 + l16;
        float bb = b1[c0];
#pragma unroll
        for (int r = 0; r < 4; ++r) {
            float v = fmaxf(acc1[nt][r] + bb, 0.f);
            hs[wv][quad * 4 + r][c0] = f2bf(v);
        }
    }

    // A frags of H from hs
    bf16x8 aH[4];
#pragma unroll
    for (int ks = 0; ks < 4; ++ks)
        aH[ks] = *(const bf16x8*)(&hs[wv][l16][ks * 32 + quad * 8]);

    // GEMM2
    f32x4 acc2[8];
#pragma unroll
    for (int nt = 0; nt < 8; ++nt) {
        f32x4 c = {0.f, 0.f, 0.f, 0.f};
#pragma unroll
        for (int ks = 0; ks < 4; ++ks)
            c = __builtin_amdgcn_mfma_f32_16x16x32_bf16(aH[ks], w2f[nt][ks], c, 0, 0, 0);
        acc2[nt] = c;
    }

    // epilogue: bias2+relu, stats, pack to hs
#pragma unroll
    for (int nt = 0; nt < 8; ++nt) {
        int c0 = nt * 16 + l16;
        float bb = b2[c0];
        float s = 0.f, sq = 0.f;
#pragma unroll
        for (int r = 0; r < 4; ++r) {
            float v = fmaxf(acc2[nt][r] + bb, 0.f);
            if (row0 + quad * 4 + r >= n) v = 0.f;
            s += v; sq += v * v;
            hs[wv][quad * 4 + r][c0] = f2bf(v);
        }
        s += __shfl_xor(s, 16); s += __shfl_xor(s, 32);
        sq += __shfl_xor(sq, 16); sq += __shfl_xor(sq, 32);
        if (quad == 0) { atomicAdd(&ssum[c0], s); atomicAdd(&ssq[c0], sq); }
    }

    // coalesced Y write from hs
    {
        int grow = row0 + l16;
        if (grow < n) {
#pragma unroll
            for (int j = 0; j < 4; ++j) {
                uint4 v = *(const uint4*)(&hs[wv][l16][quad * 32 + j * 8]);
                *(uint4*)((unsigned short*)Y + (size_t)grow * 128 + quad * 32 + j * 8) = v;
            }
        }
    }
    __syncthreads();
    if (tid < 128) {
        atomicAdd(&stats[tid], ssum[tid]);
        atomicAdd(&stats[128 + tid], ssq[tid]);
    }
}

// ---------------- BN coefs ----------------
__global__ void bn_coefs_kernel(float* __restrict__ stats, const float* __restrict__ g,
                                const float* __restrict__ bt, float* __restrict__ cA,
                                float* __restrict__ cB) {
    int c = threadIdx.x;
    float s = stats[c], sq = stats[128 + c];
    float inv_n = 1.0f / (float)NN;
    float mu = s * inv_n;
    float var = sq * inv_n - mu * mu;
    float a = g[c] * rsqrtf(var + BN_EPS);
    cA[c] = a;
    cB[c] = bt[c] - mu * a;
    stats[c] = 0.f;
    stats[128 + c] = 0.f;
}

__global__ void init_coefs_kernel(float* cA, float* cB) {
    int c = threadIdx.x;
    cA[c] = 1.f;
    cB[c] = 0.f;
}

// ---------------- pooling (bf16 input + affine) ----------------
#define POOL_CHUNK 128
__global__ void pool_kernel(const ushort16* __restrict__ h, const float* __restrict__ cA,
                            const float* __restrict__ cB, const int* __restrict__ batch,
                            float* __restrict__ pool, int n) {
    int c = threadIdx.x;   // 128 threads
    int i0 = blockIdx.x * POOL_CHUNK;
    if (i0 >= n) return;
    int i1 = min(i0 + POOL_CHUNK, n);
    const unsigned short* hp = (const unsigned short*)h;
    float a = cA[c], b = cB[c];
    float acc = 0.f;
    int cur = batch[i0];
    for (int i = i0; i < i1; ++i) {
        int g = batch[i];
        if (g != cur) {
            atomicAdd(&pool[cur * 128 + c], acc);
            acc = 0.f;
            cur = g;
        }
        acc += a * bf2f(hp[(size_t)i * 128 + c]) + b;
    }
    atomicAdd(&pool[cur * 128 + c], acc);
}

__global__ void finalize_pool_kernel(const float* __restrict__ poolA, const float* __restrict__ poolB,
                                     const float* __restrict__ cnt, float* __restrict__ meanA,
                                     float* __restrict__ meanB) {
    int g = blockIdx.x, c = threadIdx.x;
    float cc = fmaxf(cnt[g], 1.0f);
    meanA[g * 128 + c] = poolA[g * 128 + c] / cc;
    meanB[g * 128 + c] = poolB[g * 128 + c] / cc;
}

// ---------------- bilinear discriminator ----------------
__global__ void disc_kernel(const float* __restrict__ poolX, const float* __restrict__ W,
                            const float* __restrict__ db, float* __restrict__ out) {
    int g = blockIdx.x, e = threadIdx.x;    // 128 threads
    __shared__ float rs[128], rh[128];
    const float* a = poolX + g * 128;
    float t = 0.f;
    for (int d = 0; d < 128; ++d) t += a[d] * W[d * 128 + e];
    int gs = (g == 32) ? 30 : (63 - g);
    rs[e] = t * poolX[g * 128 + e];
    rh[e] = t * poolX[gs * 128 + e];
    __syncthreads();
    for (int s = 64; s > 0; s >>= 1) {
        if (e < s) { rs[e] += rs[e + s]; rh[e] += rh[e + s]; }
        __syncthreads();
    }
    if (e == 0) {
        out[GG * 10 + g] = rs[0] + db[0];
        out[GG * 10 + GG + g] = rh[0] + db[0];
    }
}

// ---------------- classification head ----------------
__global__ void head_kernel(const float* __restrict__ meanA, const float* __restrict__ poolX,
                            const float* __restrict__ w1, const float* __restrict__ b1,
                            const float* __restrict__ w2, const float* __restrict__ b2,
                            float* __restrict__ out) {
    int g = blockIdx.x, j = threadIdx.x;   // 128 threads
    __shared__ float s1[128];
    __shared__ float s2[10];
    __shared__ float lse;
    const float* ma = meanA + g * 128;
    const float* px = poolX + g * 128;
    float acc = b1[j];
    for (int k = 0; k < 128; ++k) acc += ma[k] * w1[k * 128 + j];
    for (int k = 0; k < 128; ++k) acc += px[k] * w1[(128 + k) * 128 + j];
    s1[j] = fmaxf(acc, 0.f);
    __syncthreads();
    if (j < 10) {
        float a = b2[j];
        for (int k = 0; k < 128; ++k) a += s1[k] * w2[k * 10 + j];
        s2[j] = a;
    }
    __syncthreads();
    if (j == 0) {
        float m = s2[0];
        for (int o = 1; o < 10; ++o) m = fmaxf(m, s2[o]);
        float se = 0.f;
        for (int o = 0; o < 10; ++o) se += expf(s2[o] - m);
        lse = m + logf(se);
    }
    __syncthreads();
    if (j < 10) out[g * 10 + j] = s2[j] - lse;
}

extern "C" void kernel_launch(void* const* d_in, const int* in_sizes, int n_in,
                              void* d_out, int out_size, void* d_ws, size_t ws_size,
                              hipStream_t stream) {
    const float* x     = (const float*)d_in[0];
    const int*   ei    = (const int*)d_in[1];
    const int*   batch = (const int*)d_in[2];
    const float* W1a = (const float*)d_in[3];
    const float* b1a = (const float*)d_in[4];
    const float* W2a = (const float*)d_in[5];
    const float* b2a = (const float*)d_in[6];
    const float* ga  = (const float*)d_in[7];
    const float* bta = (const float*)d_in[8];
    const float* W1b = (const float*)d_in[9];
    const float* b1b = (const float*)d_in[10];
    const float* W2b = (const float*)d_in[11];
    const float* b2b = (const float*)d_in[12];
    const float* gb  = (const float*)d_in[13];
    const float* btb = (const float*)d_in[14];
    const float* lin1_w = (const float*)d_in[15];
    const float* lin1_b = (const float*)d_in[16];
    const float* lin2_w = (const float*)d_in[17];
    const float* lin2_b = (const float*)d_in[18];
    const float* disc_w = (const float*)d_in[19];
    const float* disc_b = (const float*)d_in[20];
    float* out = (float*)d_out;

    const int* src = ei;
    const int* dst = ei + EE;

    // ---- workspace layout ----
    size_t o = 0;
    auto take = [&](size_t b) { size_t p = o; o = (o + b + 255) & ~(size_t)255; return p; };
    const size_t NB2 = (size_t)NN * 128 * 2;   // bf16 feature matrix bytes
    uint8_t* w = (uint8_t*)d_ws;
    size_t o_xb   = take(NB2);
    size_t o_g0   = take(NB2);
    size_t o_bufA = take(NB2);
    size_t o_bufB = take(NB2);
    size_t o_wf   = take((size_t)2 * 3 * 2 * MAT_STRIDE * 2);
    size_t o_col  = take((size_t)EE * 4);
    size_t o_rowstart = take((size_t)(NN + 1) * 4);
    size_t o_partials = take(512);
    size_t zero_begin = o;
    size_t o_deg    = take((size_t)NN * 4);
    size_t o_cursor = take((size_t)NN * 4);
    size_t o_stats  = take(256 * 4);
    size_t o_cnt    = take(GG * 4);
    size_t o_poolA  = take((size_t)GG * 128 * 4);
    size_t o_poolB  = take((size_t)GG * 128 * 4);
    size_t zero_end = o;
    size_t o_cA = take(128 * 4);
    size_t o_cB = take(128 * 4);
    size_t o_meanA = take((size_t)GG * 128 * 4);
    size_t o_meanB = take((size_t)GG * 128 * 4);

    ushort16* xb   = (ushort16*)(w + o_xb);
    ushort16* g0   = (ushort16*)(w + o_g0);
    ushort16* bufA = (ushort16*)(w + o_bufA);
    ushort16* bufB = (ushort16*)(w + o_bufB);
    ushort16* wf   = (ushort16*)(w + o_wf);
    int* col = (int*)(w + o_col);
    int* rowstart = (int*)(w + o_rowstart);
    int* partials = (int*)(w + o_partials);
    int* deg = (int*)(w + o_deg);
    int* cursor = (int*)(w + o_cursor);
    float* stats = (float*)(w + o_stats);
    float* cnt = (float*)(w + o_cnt);
    float* poolA = (float*)(w + o_poolA);
    float* poolB = (float*)(w + o_poolB);
    float* cA = (float*)(w + o_cA);
    float* cB = (float*)(w + o_cB);
    float* meanA = (float*)(w + o_meanA);
    float* meanB = (float*)(w + o_meanB);

    hipMemsetAsync(w + zero_begin, 0, zero_end - zero_begin, stream);

    // conversions
    x_to_bf16_kernel<<<(NN * 32 + 255) / 256, 256, 0, stream>>>(x, xb);
    convert_w_kernel<<<(24576 + 255) / 256, 256, 0, stream>>>(W1a, W2a, W1b, W2b, wf);

    // CSR build (by dst)
    int ebl = (EE + 255) / 256;
    deg_kernel<<<ebl, 256, 0, stream>>>(dst, deg);
    int nScanBlocks = (NN + 1023) / 1024;
    scan_block_kernel<<<nScanBlocks, 1024, 0, stream>>>(deg, rowstart, partials, NN);
    scan_partials_kernel<<<1, 64, 0, stream>>>(partials, nScanBlocks);
    add_offsets_kernel<<<(NN + 1 + 255) / 256, 256, 0, stream>>>(rowstart, partials, NN, EE);
    fill_col_kernel<<<ebl, 256, 0, stream>>>(src, dst, rowstart, cursor, col);
    counts_kernel<<<(NN + 255) / 256, 256, 0, stream>>>(batch, cnt, NN);

    int gatherBlocks = (NN + 3) / 4;
    int mlpBlocks = (NN + 63) / 64;

    // shared layer-0 gather (identity affine for both branches)
    init_coefs_kernel<<<1, 128, 0, stream>>>(cA, cB);
    gather_kernel<<<gatherBlocks, 256, 0, stream>>>(xb, rowstart, col, cA, cB, g0, NN);

    for (int br = 0; br < 2; ++br) {
        const float* B1 = br ? b1b : b1a;
        const float* B2 = br ? b2b : b2a;
        const float* Gm = br ? gb : ga;
        const float* Bt = br ? btb : bta;
        float* pool = br ? poolB : poolA;

        const ushort16* gin = g0;
        for (int l = 0; l < LL; ++l) {
            const ushort16* Wl = (const ushort16*)((const unsigned short*)wf +
                                                   (size_t)(br * 3 + l) * 2 * MAT_STRIDE);
            mlp_fused_kernel<<<mlpBlocks, 256, 0, stream>>>(
                gin, Wl, B1 + l * 128, B2 + l * 128, bufA, stats, NN);
            bn_coefs_kernel<<<1, 128, 0, stream>>>(stats, Gm + l * 128, Bt + l * 128, cA, cB);
            if (l < LL - 1) {
                gather_kernel<<<gatherBlocks, 256, 0, stream>>>(bufA, rowstart, col, cA, cB, bufB, NN);
                gin = bufB;
            }
        }
        pool_kernel<<<(NN + POOL_CHUNK - 1) / POOL_CHUNK, 128, 0, stream>>>(
            bufA, cA, cB, batch, pool, NN);
    }

    finalize_pool_kernel<<<GG, 128, 0, stream>>>(poolA, poolB, cnt, meanA, meanB);
    disc_kernel<<<GG, 128, 0, stream>>>(meanB, disc_w, disc_b, out);
    head_kernel<<<GG, 128, 0, stream>>>(meanA, meanB, lin1_w, lin1_b, lin2_w, lin2_b, out);
}

// Round 3
// 937.464 us; speedup vs baseline: 2.3977x; 1.1697x over previous
//
#include <hip/hip_runtime.h>
#include <hip/hip_bf16.h>

#define NN 100000
#define EE 1600000
#define GG 64
#define HH 128
#define LL 3
#define BN_EPS 1e-5f
#define NBUCK 196          // ceil(NN/512)
#define PART_CHUNK 8192
#define SEG_CAP 10240      // LDS col capacity per bucket (mean ~8192)

typedef __attribute__((ext_vector_type(8))) short bf16x8;
typedef __attribute__((ext_vector_type(4))) float f32x4;
typedef unsigned int uint32;
typedef unsigned short ushort16;

__device__ __forceinline__ float bflo(uint32 u) { return __uint_as_float(u << 16); }
__device__ __forceinline__ float bfhi(uint32 u) { return __uint_as_float(u & 0xffff0000u); }
__device__ __forceinline__ unsigned short f2bf(float f) {
    uint32 x = __float_as_uint(f);
    uint32 r = (x + 0x7fffu + ((x >> 16) & 1u)) >> 16;
    return (unsigned short)r;
}
__device__ __forceinline__ float bf2f(unsigned short u) { return __uint_as_float(((uint32)u) << 16); }

// ---------------- CSR build: degree + scan ----------------
__global__ void deg_kernel(const int* __restrict__ dst, int* __restrict__ deg) {
    int e = blockIdx.x * 256 + threadIdx.x;
    if (e < EE) atomicAdd(&deg[dst[e]], 1);
}

__global__ void scan_block_kernel(const int* __restrict__ deg, int* __restrict__ rowstart,
                                  int* __restrict__ partials, int n) {
    __shared__ int s[1024];
    int tid = threadIdx.x;
    int i = blockIdx.x * 1024 + tid;
    int v = (i < n) ? deg[i] : 0;
    s[tid] = v;
    __syncthreads();
    for (int off = 1; off < 1024; off <<= 1) {
        int t = (tid >= off) ? s[tid - off] : 0;
        __syncthreads();
        s[tid] += t;
        __syncthreads();
    }
    if (i < n) rowstart[i] = s[tid] - v;   // exclusive
    if (tid == 1023) partials[blockIdx.x] = s[1023];
}

__global__ void scan_partials_kernel(int* partials, int nb) {
    if (blockIdx.x == 0 && threadIdx.x == 0) {
        int acc = 0;
        for (int i = 0; i < nb; ++i) { int v = partials[i]; partials[i] = acc; acc += v; }
    }
}

__global__ void add_offsets_kernel(int* __restrict__ rowstart, const int* __restrict__ partials,
                                   int n, int total) {
    int i = blockIdx.x * 256 + threadIdx.x;
    if (i < n) rowstart[i] += partials[i >> 10];
    if (i == n) rowstart[n] = total;
}

__global__ void init_bcur_kernel(const int* __restrict__ rowstart, int* __restrict__ bcur) {
    int b = threadIdx.x + blockIdx.x * 256;
    if (b < NBUCK) bcur[b] = rowstart[b << 9];
}

// ---------------- bucketed edge partition ----------------
// pack src (17 bits) | dst_local (9 bits) << 17
__global__ __launch_bounds__(256) void partition_kernel(
    const int* __restrict__ src, const int* __restrict__ dst,
    int* __restrict__ bcur, uint32* __restrict__ part) {
    __shared__ int cnt[NBUCK];
    __shared__ int loff[NBUCK + 1];
    __shared__ int gpos[NBUCK];
    __shared__ int lcur[NBUCK];
    __shared__ uint32 buf[PART_CHUNK];
    int tid = threadIdx.x;
    int base = blockIdx.x * PART_CHUNK;
    int n = min(PART_CHUNK, EE - base);
    for (int i = tid; i < NBUCK; i += 256) { cnt[i] = 0; lcur[i] = 0; }
    __syncthreads();
    for (int i = tid; i < n; i += 256) atomicAdd(&cnt[dst[base + i] >> 9], 1);
    __syncthreads();
    if (tid == 0) {
        int acc = 0;
        for (int b = 0; b < NBUCK; ++b) { loff[b] = acc; acc += cnt[b]; }
        loff[NBUCK] = acc;
    }
    __syncthreads();
    if (tid < NBUCK && cnt[tid] > 0) gpos[tid] = atomicAdd(&bcur[tid], cnt[tid]);
    __syncthreads();
    for (int i = tid; i < n; i += 256) {
        int d = dst[base + i];
        int s = src[base + i];
        int b = d >> 9;
        int slot = atomicAdd(&lcur[b], 1);
        buf[loff[b] + slot] = (uint32)s | ((uint32)(d & 511) << 17);
    }
    __syncthreads();
    for (int i = tid; i < n; i += 256) {
        int lo = 0, hi = NBUCK;
        while (hi - lo > 1) { int mid = (lo + hi) >> 1; if (loff[mid] <= i) lo = mid; else hi = mid; }
        part[gpos[lo] + (i - loff[lo])] = buf[i];
    }
}

// ---------------- build col per bucket (in LDS) ----------------
__global__ __launch_bounds__(256) void build_col_kernel(
    const uint32* __restrict__ part, const int* __restrict__ rowstart,
    int* __restrict__ col, int* __restrict__ gcur) {
    __shared__ int rows[513];
    __shared__ int lcur[512];
    __shared__ int cl[SEG_CAP];
    int b = blockIdx.x;
    int tid = threadIdx.x;
    int node0 = b << 9;
    int node1 = min(node0 + 512, NN);
    int nn = node1 - node0;
    for (int i = tid; i <= nn; i += 256) rows[i] = rowstart[node0 + i];
    for (int i = tid; i < nn; i += 256) lcur[i] = 0;
    __syncthreads();
    int seg0 = rows[0];
    int len = rows[nn] - seg0;
    if (len <= SEG_CAP) {
        for (int i = tid; i < len; i += 256) {
            uint32 v = part[seg0 + i];
            int dl = (int)(v >> 17);
            int pos = atomicAdd(&lcur[dl], 1);
            cl[rows[dl] - seg0 + pos] = (int)(v & 0x1FFFFu);
        }
        __syncthreads();
        for (int i = tid; i < len; i += 256) col[seg0 + i] = cl[i];
    } else {
        for (int i = tid; i < len; i += 256) {
            uint32 v = part[seg0 + i];
            int dl = (int)(v >> 17);
            int pos = atomicAdd(&gcur[node0 + dl], 1);
            col[rows[dl] + pos] = (int)(v & 0x1FFFFu);
        }
    }
}

// ---------------- graph counts ----------------
__global__ void counts_kernel(const int* __restrict__ batch, float* __restrict__ cnt, int n) {
    __shared__ int h[GG];
    int tid = threadIdx.x;
    if (tid < GG) h[tid] = 0;
    __syncthreads();
    int i = blockIdx.x * 256 + tid;
    if (i < n) atomicAdd(&h[batch[i]], 1);
    __syncthreads();
    if (tid < GG && h[tid]) atomicAdd(&cnt[tid], (float)h[tid]);
}

// ---------------- conversions ----------------
__global__ void x_to_bf16_kernel(const float* __restrict__ x, uint32* __restrict__ xb) {
    int i = blockIdx.x * 256 + threadIdx.x;   // each handles 4 floats
    if (i < NN * 32) {
        float4 v = ((const float4*)x)[i];
        uint2 o;
        o.x = (uint32)f2bf(v.x) | ((uint32)f2bf(v.y) << 16);
        o.y = (uint32)f2bf(v.z) | ((uint32)f2bf(v.w) << 16);
        ((uint2*)xb)[i] = o;
    }
}

#define MAT_STRIDE 16384   // ushort elements per frag-ordered matrix

// frag-order weights: [br(2)][l(3)][mat(2)][nt(8)][ks(4)][lane(64)][j(8)]
__global__ void convert_w_kernel(const float* __restrict__ W1a, const float* __restrict__ W2a,
                                 const float* __restrict__ W1b, const float* __restrict__ W2b,
                                 unsigned short* __restrict__ out) {
    int t = blockIdx.x * 256 + threadIdx.x;
    if (t >= 24576) return;
    int lane = t & 63;
    int r = t >> 6;
    int ks = r & 3; r >>= 2;
    int nt = r & 7; r >>= 3;
    int mat = r & 1; r >>= 1;
    int l = r % 3, br = r / 3;
    const float* W = br ? (mat ? W2b : W1b) : (mat ? W2a : W1a);
    const float* Wl = W + (size_t)l * 128 * 128;
    int n0 = nt * 16 + (lane & 15);
    int k0 = ks * 32 + (lane >> 4) * 8;
    unsigned short tmp[8];
#pragma unroll
    for (int j = 0; j < 8; ++j) tmp[j] = f2bf(Wl[(size_t)(k0 + j) * 128 + n0]);
    size_t seq = (size_t)(br * 3 + l) * 2 + mat;
    size_t off = (((seq * 8 + nt) * 4 + ks) * 64 + (size_t)lane) * 8;
    *(uint4*)(out + off) = *(const uint4*)tmp;
}

// ---------------- layer-0 gather: g0[i] = bf16( x[i] + sum_j x[j] ), 128ch ----------------
__global__ void gather0_kernel(const uint32* __restrict__ h32, const int* __restrict__ rowstart,
                               const int* __restrict__ col, uint32* __restrict__ out) {
    int gw = (blockIdx.x * blockDim.x + threadIdx.x) >> 6;
    int lane = threadIdx.x & 63;
    if (gw >= NN) return;
    uint32 self = h32[(size_t)gw * 64 + lane];
    float a0 = bflo(self), a1 = bfhi(self);
    float b0 = 0.f, b1 = 0.f, c0 = 0.f, c1 = 0.f, d0 = 0.f, d1 = 0.f;
    int beg = rowstart[gw], end = rowstart[gw + 1];
    int e = beg;
    for (; e + 8 <= end; e += 8) {
        uint32 u0 = h32[(size_t)col[e] * 64 + lane];
        uint32 u1 = h32[(size_t)col[e + 1] * 64 + lane];
        uint32 u2 = h32[(size_t)col[e + 2] * 64 + lane];
        uint32 u3 = h32[(size_t)col[e + 3] * 64 + lane];
        uint32 u4 = h32[(size_t)col[e + 4] * 64 + lane];
        uint32 u5 = h32[(size_t)col[e + 5] * 64 + lane];
        uint32 u6 = h32[(size_t)col[e + 6] * 64 + lane];
        uint32 u7 = h32[(size_t)col[e + 7] * 64 + lane];
        a0 += bflo(u0); a1 += bfhi(u0); b0 += bflo(u1); b1 += bfhi(u1);
        c0 += bflo(u2); c1 += bfhi(u2); d0 += bflo(u3); d1 += bfhi(u3);
        a0 += bflo(u4); a1 += bfhi(u4); b0 += bflo(u5); b1 += bfhi(u5);
        c0 += bflo(u6); c1 += bfhi(u6); d0 += bflo(u7); d1 += bfhi(u7);
    }
    for (; e < end; ++e) {
        uint32 u = h32[(size_t)col[e] * 64 + lane];
        a0 += bflo(u); a1 += bfhi(u);
    }
    float ox = (a0 + b0) + (c0 + d0);
    float oy = (a1 + b1) + (c1 + d1);
    out[(size_t)gw * 64 + lane] = (uint32)f2bf(ox) | ((uint32)f2bf(oy) << 16);
}

// ---------------- dual-branch gather on concat [N,256] features ----------------
// out[i][c] = bf16( A_c*(h[i][c] + sum_j h[j][c]) + B_c*(deg+1) ), coefs from BN stats of layer lprev
__global__ void gather_dual_kernel(const uint2* __restrict__ h2, const int* __restrict__ rowstart,
                                   const int* __restrict__ col, const float* __restrict__ stats,
                                   const float* __restrict__ ga, const float* __restrict__ bta,
                                   const float* __restrict__ gb, const float* __restrict__ btb,
                                   int lprev, uint2* __restrict__ out) {
    int gw = (blockIdx.x * blockDim.x + threadIdx.x) >> 6;
    int lane = threadIdx.x & 63;
    if (gw >= NN) return;
    // channels c = lane*4 + j, j=0..3; branch = lanes>=32
    int br = lane >> 5;
    const float* st = stats + (size_t)(lprev * 2 + br) * 256;
    const float* gmp = (br ? gb : ga) + lprev * 128;
    const float* btp = (br ? btb : bta) + lprev * 128;
    int cc0 = (lane * 4) & 127;
    float A[4], B[4];
#pragma unroll
    for (int j = 0; j < 4; ++j) {
        float s = st[cc0 + j], sq = st[128 + cc0 + j];
        float mu = s * (1.f / NN);
        float var = sq * (1.f / NN) - mu * mu;
        float a = gmp[cc0 + j] * rsqrtf(var + BN_EPS);
        A[j] = a;
        B[j] = btp[cc0 + j] - mu * a;
    }
    uint2 self = h2[(size_t)gw * 64 + lane];
    float p0 = bflo(self.x), p1 = bfhi(self.x), p2 = bflo(self.y), p3 = bfhi(self.y);
    float q0 = 0.f, q1 = 0.f, q2 = 0.f, q3 = 0.f;
    int beg = rowstart[gw], end = rowstart[gw + 1];
    float degp1 = (float)(end - beg + 1);
    int e = beg;
    for (; e + 4 <= end; e += 4) {
        uint2 u0 = h2[(size_t)col[e] * 64 + lane];
        uint2 u1 = h2[(size_t)col[e + 1] * 64 + lane];
        uint2 u2 = h2[(size_t)col[e + 2] * 64 + lane];
        uint2 u3 = h2[(size_t)col[e + 3] * 64 + lane];
        p0 += bflo(u0.x); p1 += bfhi(u0.x); p2 += bflo(u0.y); p3 += bfhi(u0.y);
        q0 += bflo(u1.x); q1 += bfhi(u1.x); q2 += bflo(u1.y); q3 += bfhi(u1.y);
        p0 += bflo(u2.x); p1 += bfhi(u2.x); p2 += bflo(u2.y); p3 += bfhi(u2.y);
        q0 += bflo(u3.x); q1 += bfhi(u3.x); q2 += bflo(u3.y); q3 += bfhi(u3.y);
    }
    for (; e < end; ++e) {
        uint2 u = h2[(size_t)col[e] * 64 + lane];
        p0 += bflo(u.x); p1 += bfhi(u.x); p2 += bflo(u.y); p3 += bfhi(u.y);
    }
    float o0 = A[0] * (p0 + q0) + B[0] * degp1;
    float o1 = A[1] * (p1 + q1) + B[1] * degp1;
    float o2 = A[2] * (p2 + q2) + B[2] * degp1;
    float o3 = A[3] * (p3 + q3) + B[3] * degp1;
    uint2 o;
    o.x = (uint32)f2bf(o0) | ((uint32)f2bf(o1) << 16);
    o.y = (uint32)f2bf(o2) | ((uint32)f2bf(o3) << 16);
    out[(size_t)gw * 64 + lane] = o;
}

// ---------------- fused dual-branch MLP ----------------
// blockIdx.y = branch. Y(concat, stride 256, off br*128) = relu(relu(X@W1+b1)@W2+b2); BN stats.
__global__ __launch_bounds__(256, 2) void mlp_dual_kernel(
    const unsigned short* __restrict__ X, int in_stride, int in_off_mul,
    const unsigned short* __restrict__ wf_all,
    const float* __restrict__ b1a, const float* __restrict__ b1b,
    const float* __restrict__ b2a, const float* __restrict__ b2b,
    int l, unsigned short* __restrict__ Y, float* __restrict__ stats, int n) {
    __shared__ unsigned short w1s[MAT_STRIDE];     // 32 KB
    __shared__ unsigned short hs[4][16][136];      // 17.4 KB
    __shared__ float ssum[128], ssq[128];

    int br = blockIdx.y;
    const unsigned short* Wf = wf_all + (size_t)(br * 3 + l) * 2 * MAT_STRIDE;
    const float* b1 = (br ? b1b : b1a) + l * 128;
    const float* b2 = (br ? b2b : b2a) + l * 128;
    float* statsp = stats + (size_t)(l * 2 + br) * 256;
    int in_off = in_off_mul * br;

    int tid = threadIdx.x;
    int wv = tid >> 6, lane = tid & 63;
    int quad = lane >> 4, l16 = lane & 15;

    {
        const uint4* srcp = (const uint4*)Wf;
        uint4* dstp = (uint4*)w1s;
        for (int i = tid; i < 2048; i += 256) dstp[i] = srcp[i];
    }
    if (tid < 128) { ssum[tid] = 0.f; ssq[tid] = 0.f; }
    __syncthreads();

    bf16x8 w2f[8][4];
    {
        const bf16x8* w2g = (const bf16x8*)(Wf + MAT_STRIDE);
#pragma unroll
        for (int nt = 0; nt < 8; ++nt)
#pragma unroll
            for (int ks = 0; ks < 4; ++ks) w2f[nt][ks] = w2g[(nt * 4 + ks) * 64 + lane];
    }

    int row0 = blockIdx.x * 64 + wv * 16;

    bf16x8 aF[4];
    {
        int r = row0 + l16;
        if (r >= n) r = n - 1;
        const unsigned short* xrow = X + (size_t)r * in_stride + in_off;
#pragma unroll
        for (int ks = 0; ks < 4; ++ks) aF[ks] = *(const bf16x8*)(xrow + ks * 32 + quad * 8);
    }

    f32x4 acc1[8];
#pragma unroll
    for (int nt = 0; nt < 8; ++nt) {
        f32x4 c = {0.f, 0.f, 0.f, 0.f};
#pragma unroll
        for (int ks = 0; ks < 4; ++ks) {
            bf16x8 bfrag = *(const bf16x8*)(&w1s[((nt * 4 + ks) * 64 + lane) * 8]);
            c = __builtin_amdgcn_mfma_f32_16x16x32_bf16(aF[ks], bfrag, c, 0, 0, 0);
        }
        acc1[nt] = c;
    }

#pragma unroll
    for (int nt = 0; nt < 8; ++nt) {
        int c0 = nt * 16 + l16;
        float bb = b1[c0];
#pragma unroll
        for (int r = 0; r < 4; ++r) {
            float v = fmaxf(acc1[nt][r] + bb, 0.f);
            hs[wv][quad * 4 + r][c0] = f2bf(v);
        }
    }

    bf16x8 aH[4];
#pragma unroll
    for (int ks = 0; ks < 4; ++ks)
        aH[ks] = *(const bf16x8*)(&hs[wv][l16][ks * 32 + quad * 8]);

    f32x4 acc2[8];
#pragma unroll
    for (int nt = 0; nt < 8; ++nt) {
        f32x4 c = {0.f, 0.f, 0.f, 0.f};
#pragma unroll
        for (int ks = 0; ks < 4; ++ks)
            c = __builtin_amdgcn_mfma_f32_16x16x32_bf16(aH[ks], w2f[nt][ks], c, 0, 0, 0);
        acc2[nt] = c;
    }

#pragma unroll
    for (int nt = 0; nt < 8; ++nt) {
        int c0 = nt * 16 + l16;
        float bb = b2[c0];
        float s = 0.f, sq = 0.f;
#pragma unroll
        for (int r = 0; r < 4; ++r) {
            float v = fmaxf(acc2[nt][r] + bb, 0.f);
            if (row0 + quad * 4 + r >= n) v = 0.f;
            s += v; sq += v * v;
            hs[wv][quad * 4 + r][c0] = f2bf(v);
        }
        s += __shfl_xor(s, 16); s += __shfl_xor(s, 32);
        sq += __shfl_xor(sq, 16); sq += __shfl_xor(sq, 32);
        if (quad == 0) { atomicAdd(&ssum[c0], s); atomicAdd(&ssq[c0], sq); }
    }

    {
        int grow = row0 + l16;
        if (grow < n) {
#pragma unroll
            for (int j = 0; j < 4; ++j) {
                uint4 v = *(const uint4*)(&hs[wv][l16][quad * 32 + j * 8]);
                *(uint4*)(Y + (size_t)grow * 256 + br * 128 + quad * 32 + j * 8) = v;
            }
        }
    }
    __syncthreads();
    if (tid < 128) {
        atomicAdd(&statsp[tid], ssum[tid]);
        atomicAdd(&statsp[128 + tid], ssq[tid]);
    }
}

// ---------------- dual pooling from concat buffer ----------------
#define POOL_CHUNK 128
__global__ void pool_dual_kernel(const unsigned short* __restrict__ h,
                                 const float* __restrict__ stats,
                                 const float* __restrict__ ga, const float* __restrict__ bta,
                                 const float* __restrict__ gb, const float* __restrict__ btb,
                                 const int* __restrict__ batch,
                                 float* __restrict__ poolA, float* __restrict__ poolB, int n) {
    int t = threadIdx.x;       // 256 threads: ch t of concat row
    int br = t >> 7, cc = t & 127;
    const float* st = stats + (size_t)(2 * 2 + br) * 256;   // layer 2 stats
    float s = st[cc], sq = st[128 + cc];
    float mu = s * (1.f / NN);
    float var = sq * (1.f / NN) - mu * mu;
    float gm = (br ? gb : ga)[2 * 128 + cc];
    float a = gm * rsqrtf(var + BN_EPS);
    float b = (br ? btb : bta)[2 * 128 + cc] - mu * a;
    float* pool = br ? poolB : poolA;

    int i0 = blockIdx.x * POOL_CHUNK;
    if (i0 >= n) return;
    int i1 = min(i0 + POOL_CHUNK, n);
    float acc = 0.f;
    int cur = batch[i0];
    for (int i = i0; i < i1; ++i) {
        int g = batch[i];
        if (g != cur) {
            atomicAdd(&pool[cur * 128 + cc], acc);
            acc = 0.f;
            cur = g;
        }
        acc += a * bf2f(h[(size_t)i * 256 + t]) + b;
    }
    atomicAdd(&pool[cur * 128 + cc], acc);
}

// ---------------- bilinear discriminator (mean inline) ----------------
__global__ void disc_kernel(const float* __restrict__ poolB, const float* __restrict__ cnt,
                            const float* __restrict__ W, const float* __restrict__ db,
                            float* __restrict__ out) {
    int g = blockIdx.x, e = threadIdx.x;    // 128 threads
    __shared__ float rs[128], rh[128];
    float invc = 1.f / fmaxf(cnt[g], 1.f);
    int gs = (g == 32) ? 30 : (63 - g);
    float invcs = 1.f / fmaxf(cnt[gs], 1.f);
    const float* a = poolB + g * 128;
    float t = 0.f;
    for (int d = 0; d < 128; ++d) t += a[d] * W[d * 128 + e];
    t *= invc;
    rs[e] = t * poolB[g * 128 + e] * invc;
    rh[e] = t * poolB[gs * 128 + e] * invcs;
    __syncthreads();
    for (int s = 64; s > 0; s >>= 1) {
        if (e < s) { rs[e] += rs[e + s]; rh[e] += rh[e + s]; }
        __syncthreads();
    }
    if (e == 0) {
        out[GG * 10 + g] = rs[0] + db[0];
        out[GG * 10 + GG + g] = rh[0] + db[0];
    }
}

// ---------------- classification head (mean inline) ----------------
__global__ void head_kernel(const float* __restrict__ poolA, const float* __restrict__ poolB,
                            const float* __restrict__ cnt,
                            const float* __restrict__ w1, const float* __restrict__ b1,
                            const float* __restrict__ w2, const float* __restrict__ b2,
                            float* __restrict__ out) {
    int g = blockIdx.x, j = threadIdx.x;   // 128 threads
    __shared__ float s1[128];
    __shared__ float s2[10];
    __shared__ float lse;
    float invc = 1.f / fmaxf(cnt[g], 1.f);
    const float* ma = poolA + g * 128;
    const float* px = poolB + g * 128;
    float acc = b1[j];
    for (int k = 0; k < 128; ++k) acc += ma[k] * invc * w1[k * 128 + j];
    for (int k = 0; k < 128; ++k) acc += px[k] * invc * w1[(128 + k) * 128 + j];
    s1[j] = fmaxf(acc, 0.f);
    __syncthreads();
    if (j < 10) {
        float a = b2[j];
        for (int k = 0; k < 128; ++k) a += s1[k] * w2[k * 10 + j];
        s2[j] = a;
    }
    __syncthreads();
    if (j == 0) {
        float m = s2[0];
        for (int o = 1; o < 10; ++o) m = fmaxf(m, s2[o]);
        float se = 0.f;
        for (int o = 0; o < 10; ++o) se += expf(s2[o] - m);
        lse = m + logf(se);
    }
    __syncthreads();
    if (j < 10) out[g * 10 + j] = s2[j] - lse;
}

extern "C" void kernel_launch(void* const* d_in, const int* in_sizes, int n_in,
                              void* d_out, int out_size, void* d_ws, size_t ws_size,
                              hipStream_t stream) {
    const float* x     = (const float*)d_in[0];
    const int*   ei    = (const int*)d_in[1];
    const int*   batch = (const int*)d_in[2];
    const float* W1a = (const float*)d_in[3];
    const float* b1a = (const float*)d_in[4];
    const float* W2a = (const float*)d_in[5];
    const float* b2a = (const float*)d_in[6];
    const float* ga  = (const float*)d_in[7];
    const float* bta = (const float*)d_in[8];
    const float* W1b = (const float*)d_in[9];
    const float* b1b = (const float*)d_in[10];
    const float* W2b = (const float*)d_in[11];
    const float* b2b = (const float*)d_in[12];
    const float* gb  = (const float*)d_in[13];
    const float* btb = (const float*)d_in[14];
    const float* lin1_w = (const float*)d_in[15];
    const float* lin1_b = (const float*)d_in[16];
    const float* lin2_w = (const float*)d_in[17];
    const float* lin2_b = (const float*)d_in[18];
    const float* disc_w = (const float*)d_in[19];
    const float* disc_b = (const float*)d_in[20];
    float* out = (float*)d_out;

    const int* src = ei;
    const int* dst = ei + EE;

    // ---- workspace layout ----
    size_t o = 0;
    auto take = [&](size_t b) { size_t p = o; o = (o + b + 255) & ~(size_t)255; return p; };
    uint8_t* w = (uint8_t*)d_ws;
    size_t o_xb   = take((size_t)NN * 128 * 2);   // bf16 x
    size_t o_g0   = take((size_t)NN * 128 * 2);   // shared layer-0 gather
    size_t o_bufP = take((size_t)NN * 256 * 2);   // concat layer outputs
    size_t o_gbuf = take((size_t)NN * 256 * 2);   // concat gathered
    size_t o_wf   = take((size_t)12 * MAT_STRIDE * 2);
    size_t o_col  = take((size_t)EE * 4);
    size_t o_part = take((size_t)EE * 4);
    size_t o_rowstart = take((size_t)(NN + 1) * 4);
    size_t o_partials = take(512);
    size_t o_bcur = take((size_t)NBUCK * 4);
    size_t zero_begin = o;
    size_t o_deg    = take((size_t)NN * 4);
    size_t o_gcur   = take((size_t)NN * 4);
    size_t o_stats  = take((size_t)6 * 256 * 4);
    size_t o_cnt    = take(GG * 4);
    size_t o_poolA  = take((size_t)GG * 128 * 4);
    size_t o_poolB  = take((size_t)GG * 128 * 4);
    size_t zero_end = o;

    uint32* xb = (uint32*)(w + o_xb);
    uint32* g0 = (uint32*)(w + o_g0);
    unsigned short* bufP = (unsigned short*)(w + o_bufP);
    unsigned short* gbuf = (unsigned short*)(w + o_gbuf);
    unsigned short* wf = (unsigned short*)(w + o_wf);
    int* col = (int*)(w + o_col);
    uint32* part = (uint32*)(w + o_part);
    int* rowstart = (int*)(w + o_rowstart);
    int* partials = (int*)(w + o_partials);
    int* bcur = (int*)(w + o_bcur);
    int* deg = (int*)(w + o_deg);
    int* gcur = (int*)(w + o_gcur);
    float* stats = (float*)(w + o_stats);
    float* cnt = (float*)(w + o_cnt);
    float* poolA = (float*)(w + o_poolA);
    float* poolB = (float*)(w + o_poolB);

    hipMemsetAsync(w + zero_begin, 0, zero_end - zero_begin, stream);

    // conversions (independent of CSR)
    x_to_bf16_kernel<<<(NN * 32 + 255) / 256, 256, 0, stream>>>(x, xb);
    convert_w_kernel<<<(24576 + 255) / 256, 256, 0, stream>>>(W1a, W2a, W1b, W2b, wf);

    // CSR build
    deg_kernel<<<(EE + 255) / 256, 256, 0, stream>>>(dst, deg);
    int nScanBlocks = (NN + 1023) / 1024;
    scan_block_kernel<<<nScanBlocks, 1024, 0, stream>>>(deg, rowstart, partials, NN);
    scan_partials_kernel<<<1, 64, 0, stream>>>(partials, nScanBlocks);
    add_offsets_kernel<<<(NN + 1 + 255) / 256, 256, 0, stream>>>(rowstart, partials, NN, EE);
    init_bcur_kernel<<<1, 256, 0, stream>>>(rowstart, bcur);
    partition_kernel<<<(EE + PART_CHUNK - 1) / PART_CHUNK, 256, 0, stream>>>(src, dst, bcur, part);
    build_col_kernel<<<NBUCK, 256, 0, stream>>>(part, rowstart, col, gcur);
    counts_kernel<<<(NN + 255) / 256, 256, 0, stream>>>(batch, cnt, NN);

    int gatherBlocks = (NN + 3) / 4;   // 4 node-waves per block
    dim3 mlpGrid((NN + 63) / 64, 2);

    // shared layer-0 gather
    gather0_kernel<<<gatherBlocks, 256, 0, stream>>>(xb, rowstart, col, g0);

    // layer 0 (both branches read g0)
    mlp_dual_kernel<<<mlpGrid, 256, 0, stream>>>(
        (const unsigned short*)g0, 128, 0, wf, b1a, b1b, b2a, b2b, 0, bufP, stats, NN);
    // layers 1..2
    for (int l = 1; l < LL; ++l) {
        gather_dual_kernel<<<gatherBlocks, 256, 0, stream>>>(
            (const uint2*)bufP, rowstart, col, stats, ga, bta, gb, btb, l - 1, (uint2*)gbuf);
        mlp_dual_kernel<<<mlpGrid, 256, 0, stream>>>(
            gbuf, 256, 128, wf, b1a, b1b, b2a, b2b, l, bufP, stats, NN);
    }

    pool_dual_kernel<<<(NN + POOL_CHUNK - 1) / POOL_CHUNK, 256, 0, stream>>>(
        bufP, stats, ga, bta, gb, btb, batch, poolA, poolB, NN);
    disc_kernel<<<GG, 128, 0, stream>>>(poolB, cnt, disc_w, disc_b, out);
    head_kernel<<<GG, 128, 0, stream>>>(poolA, poolB, cnt, lin1_w, lin1_b, lin2_w, lin2_b, out);
}

// Round 4
// 852.035 us; speedup vs baseline: 2.6381x; 1.1003x over previous
//
#include <hip/hip_runtime.h>
#include <hip/hip_bf16.h>

#define NN 100000
#define EE 1600000
#define GG 64
#define HH 128
#define LL 3
#define BN_EPS 1e-5f
#define NBUCK 196          // ceil(NN/512)
#define BCAP 12288         // bucket capacity (mean 8163, +45 sigma safe)
#define PART_CHUNK 8192

typedef __attribute__((ext_vector_type(8))) short bf16x8;
typedef __attribute__((ext_vector_type(4))) float f32x4;
typedef unsigned int uint32;

__device__ __forceinline__ float bflo(uint32 u) { return __uint_as_float(u << 16); }
__device__ __forceinline__ float bfhi(uint32 u) { return __uint_as_float(u & 0xffff0000u); }
__device__ __forceinline__ unsigned short f2bf(float f) {
    uint32 x = __float_as_uint(f);
    uint32 r = (x + 0x7fffu + ((x >> 16) & 1u)) >> 16;
    return (unsigned short)r;
}
__device__ __forceinline__ float bf2f(unsigned short u) { return __uint_as_float(((uint32)u) << 16); }
__device__ __forceinline__ void acc2(float2& a, uint32 u) { a.x += bflo(u); a.y += bfhi(u); }

// ---------------- bucketed edge partition (fixed-capacity buckets) ----------------
// pack src (17 bits) | dst_local (9 bits) << 17
__global__ __launch_bounds__(256) void partition_kernel(
    const int* __restrict__ src, const int* __restrict__ dst,
    int* __restrict__ bcnt, uint32* __restrict__ part) {
    __shared__ int cnt[NBUCK];
    __shared__ int loff[NBUCK + 1];
    __shared__ int gpos[NBUCK];
    __shared__ int lcur[NBUCK];
    __shared__ uint32 buf[PART_CHUNK];
    int tid = threadIdx.x;
    int base = blockIdx.x * PART_CHUNK;
    int n = min(PART_CHUNK, EE - base);
    for (int i = tid; i < NBUCK; i += 256) { cnt[i] = 0; lcur[i] = 0; }
    __syncthreads();
    for (int i = tid; i < n; i += 256) atomicAdd(&cnt[dst[base + i] >> 9], 1);
    __syncthreads();
    if (tid == 0) {
        int acc = 0;
        for (int b = 0; b < NBUCK; ++b) { loff[b] = acc; acc += cnt[b]; }
        loff[NBUCK] = acc;
    }
    __syncthreads();
    if (tid < NBUCK && cnt[tid] > 0) gpos[tid] = atomicAdd(&bcnt[tid], cnt[tid]);
    __syncthreads();
    for (int i = tid; i < n; i += 256) {
        int d = dst[base + i];
        int s = src[base + i];
        int b = d >> 9;
        int slot = atomicAdd(&lcur[b], 1);
        buf[loff[b] + slot] = (uint32)s | ((uint32)(d & 511) << 17);
    }
    __syncthreads();
    for (int i = tid; i < n; i += 256) {
        int lo = 0, hi = NBUCK;
        while (hi - lo > 1) { int mid = (lo + hi) >> 1; if (loff[mid] <= i) lo = mid; else hi = mid; }
        part[(size_t)lo * BCAP + gpos[lo] + (i - loff[lo])] = buf[i];
    }
}

// ---------------- build per-bucket CSR + col (all in LDS) ----------------
__global__ __launch_bounds__(256) void build_col_kernel(
    const uint32* __restrict__ part, const int* __restrict__ bcnt,
    int* __restrict__ col, int2* __restrict__ rowpair) {
    __shared__ int ldeg[512];
    __shared__ int loffn[512];
    __shared__ int lcur[512];
    __shared__ int pscan[256];
    __shared__ int cl[BCAP];
    int b = blockIdx.x;
    int tid = threadIdx.x;
    int node0 = b << 9;
    int nn = min(node0 + 512, NN) - node0;
    int cnt = bcnt[b];
    int base = b * BCAP;
    const uint32* pp = part + (size_t)base;
    for (int i = tid; i < 512; i += 256) { ldeg[i] = 0; lcur[i] = 0; }
    __syncthreads();
    for (int i = tid; i < cnt; i += 256) atomicAdd(&ldeg[pp[i] >> 17], 1);
    __syncthreads();
    int t2 = tid * 2;
    int a0 = ldeg[t2], a1 = ldeg[t2 + 1];
    int ps = a0 + a1;
    pscan[tid] = ps;
    __syncthreads();
    for (int off = 1; off < 256; off <<= 1) {
        int v = (tid >= off) ? pscan[tid - off] : 0;
        __syncthreads();
        pscan[tid] += v;
        __syncthreads();
    }
    int eo = pscan[tid] - ps;       // exclusive over pairs
    loffn[t2] = eo;
    loffn[t2 + 1] = eo + a0;
    if (t2 < nn)     rowpair[node0 + t2]     = make_int2(base + eo, base + eo + a0);
    if (t2 + 1 < nn) rowpair[node0 + t2 + 1] = make_int2(base + eo + a0, base + eo + a0 + a1);
    __syncthreads();
    for (int i = tid; i < cnt; i += 256) {
        uint32 v = pp[i];
        int dl = (int)(v >> 17);
        int pos = atomicAdd(&lcur[dl], 1);
        cl[loffn[dl] + pos] = (int)(v & 0x1FFFFu);
    }
    __syncthreads();
    for (int i = tid; i < cnt; i += 256) col[base + i] = cl[i];
}

// ---------------- graph counts ----------------
__global__ void counts_kernel(const int* __restrict__ batch, float* __restrict__ cnt, int n) {
    __shared__ int h[GG];
    int tid = threadIdx.x;
    if (tid < GG) h[tid] = 0;
    __syncthreads();
    int i = blockIdx.x * 256 + tid;
    if (i < n) atomicAdd(&h[batch[i]], 1);
    __syncthreads();
    if (tid < GG && h[tid]) atomicAdd(&cnt[tid], (float)h[tid]);
}

// ---------------- conversions ----------------
__global__ void x_to_bf16_kernel(const float* __restrict__ x, uint32* __restrict__ xb) {
    int i = blockIdx.x * 256 + threadIdx.x;   // each handles 4 floats
    if (i < NN * 32) {
        float4 v = ((const float4*)x)[i];
        uint2 o;
        o.x = (uint32)f2bf(v.x) | ((uint32)f2bf(v.y) << 16);
        o.y = (uint32)f2bf(v.z) | ((uint32)f2bf(v.w) << 16);
        ((uint2*)xb)[i] = o;
    }
}

#define MAT_STRIDE 16384   // ushort elements per frag-ordered matrix

// frag-order weights: [br(2)][l(3)][mat(2)][nt(8)][ks(4)][lane(64)][j(8)]
__global__ void convert_w_kernel(const float* __restrict__ W1a, const float* __restrict__ W2a,
                                 const float* __restrict__ W1b, const float* __restrict__ W2b,
                                 unsigned short* __restrict__ out) {
    int t = blockIdx.x * 256 + threadIdx.x;
    if (t >= 24576) return;
    int lane = t & 63;
    int r = t >> 6;
    int ks = r & 3; r >>= 2;
    int nt = r & 7; r >>= 3;
    int mat = r & 1; r >>= 1;
    int l = r % 3, br = r / 3;
    const float* W = br ? (mat ? W2b : W1b) : (mat ? W2a : W1a);
    const float* Wl = W + (size_t)l * 128 * 128;
    int n0 = nt * 16 + (lane & 15);
    int k0 = ks * 32 + (lane >> 4) * 8;
    unsigned short tmp[8];
#pragma unroll
    for (int j = 0; j < 8; ++j) tmp[j] = f2bf(Wl[(size_t)(k0 + j) * 128 + n0]);
    size_t seq = (size_t)(br * 3 + l) * 2 + mat;
    size_t off = (((seq * 8 + nt) * 4 + ks) * 64 + (size_t)lane) * 8;
    *(uint4*)(out + off) = *(const uint4*)tmp;
}

// ---------------- layer-0 gather: g0[i] = bf16( x[i] + sum_j x[j] ), 128ch ----------------
// 4 edge-slots per wave, 16 lanes x uint4 (16B) per edge row (256 B)
__global__ void gather0_kernel(const uint4* __restrict__ h4, const int2* __restrict__ rowpair,
                               const int* __restrict__ col, uint4* __restrict__ out) {
    int gw = (blockIdx.x * blockDim.x + threadIdx.x) >> 6;
    int lane = threadIdx.x & 63;
    if (gw >= NN) return;
    int slot = lane >> 4;      // 0..3
    int c8 = lane & 15;        // channels 8*c8 .. +7
    float2 acc[4] = {{0.f,0.f},{0.f,0.f},{0.f,0.f},{0.f,0.f}};
    if (slot == 0) {
        uint4 s = h4[(size_t)gw * 16 + c8];
        acc2(acc[0], s.x); acc2(acc[1], s.y); acc2(acc[2], s.z); acc2(acc[3], s.w);
    }
    int2 be = rowpair[gw];
    int beg = be.x, end = be.y;
    int e = beg;
    for (; e + 8 <= end; e += 8) {
        int j0 = col[e + slot], j1 = col[e + 4 + slot];
        uint4 u0 = h4[(size_t)j0 * 16 + c8];
        uint4 u1 = h4[(size_t)j1 * 16 + c8];
        acc2(acc[0], u0.x); acc2(acc[1], u0.y); acc2(acc[2], u0.z); acc2(acc[3], u0.w);
        acc2(acc[0], u1.x); acc2(acc[1], u1.y); acc2(acc[2], u1.z); acc2(acc[3], u1.w);
    }
    for (; e + 4 <= end; e += 4) {
        int j = col[e + slot];
        uint4 u = h4[(size_t)j * 16 + c8];
        acc2(acc[0], u.x); acc2(acc[1], u.y); acc2(acc[2], u.z); acc2(acc[3], u.w);
    }
    int rem = end - e;
    if (slot < rem) {
        int j = col[e + slot];
        uint4 u = h4[(size_t)j * 16 + c8];
        acc2(acc[0], u.x); acc2(acc[1], u.y); acc2(acc[2], u.z); acc2(acc[3], u.w);
    }
#pragma unroll
    for (int k = 0; k < 4; ++k) {
        acc[k].x += __shfl_xor(acc[k].x, 16); acc[k].y += __shfl_xor(acc[k].y, 16);
        acc[k].x += __shfl_xor(acc[k].x, 32); acc[k].y += __shfl_xor(acc[k].y, 32);
    }
    if (slot == 0) {
        uint4 r;
        r.x = (uint32)f2bf(acc[0].x) | ((uint32)f2bf(acc[0].y) << 16);
        r.y = (uint32)f2bf(acc[1].x) | ((uint32)f2bf(acc[1].y) << 16);
        r.z = (uint32)f2bf(acc[2].x) | ((uint32)f2bf(acc[2].y) << 16);
        r.w = (uint32)f2bf(acc[3].x) | ((uint32)f2bf(acc[3].y) << 16);
        out[(size_t)gw * 16 + c8] = r;
    }
}

// ---------------- dual-branch gather on concat [N,256] rows (512 B) ----------------
// 2 edge-slots per wave, 32 lanes x uint4 per edge row; BN affine folded in.
__global__ void gather_dual_kernel(const uint4* __restrict__ h4, const int2* __restrict__ rowpair,
                                   const int* __restrict__ col, const float* __restrict__ stats,
                                   const float* __restrict__ ga, const float* __restrict__ bta,
                                   const float* __restrict__ gb, const float* __restrict__ btb,
                                   int lprev, uint4* __restrict__ out) {
    int gw = (blockIdx.x * blockDim.x + threadIdx.x) >> 6;
    int lane = threadIdx.x & 63;
    if (gw >= NN) return;
    int slot = lane >> 5;      // 0..1
    int c8 = lane & 31;        // channels 8*c8 .. +7 of concat row
    int br = c8 >> 4;
    const float* st = stats + (size_t)(lprev * 2 + br) * 256;
    const float* gmp = (br ? gb : ga) + lprev * 128;
    const float* btp = (br ? btb : bta) + lprev * 128;
    int cc0 = (c8 * 8) & 127;
    float2 A[4], B[4];
#pragma unroll
    for (int k = 0; k < 4; ++k) {
        int c0 = cc0 + 2 * k;
#pragma unroll
        for (int h = 0; h < 2; ++h) {
            float s = st[c0 + h], sq = st[128 + c0 + h];
            float mu = s * (1.f / NN);
            float var = sq * (1.f / NN) - mu * mu;
            float a = gmp[c0 + h] * rsqrtf(var + BN_EPS);
            float bb = btp[c0 + h] - mu * a;
            if (h == 0) { A[k].x = a; B[k].x = bb; } else { A[k].y = a; B[k].y = bb; }
        }
    }
    float2 acc[4] = {{0.f,0.f},{0.f,0.f},{0.f,0.f},{0.f,0.f}};
    if (slot == 0) {
        uint4 s = h4[(size_t)gw * 32 + c8];
        acc2(acc[0], s.x); acc2(acc[1], s.y); acc2(acc[2], s.z); acc2(acc[3], s.w);
    }
    int2 be = rowpair[gw];
    int beg = be.x, end = be.y;
    float degp1 = (float)(end - beg + 1);
    int e = beg;
    for (; e + 8 <= end; e += 8) {
        int j0 = col[e + slot], j1 = col[e + 2 + slot];
        int j2 = col[e + 4 + slot], j3 = col[e + 6 + slot];
        uint4 u0 = h4[(size_t)j0 * 32 + c8];
        uint4 u1 = h4[(size_t)j1 * 32 + c8];
        uint4 u2 = h4[(size_t)j2 * 32 + c8];
        uint4 u3 = h4[(size_t)j3 * 32 + c8];
        acc2(acc[0], u0.x); acc2(acc[1], u0.y); acc2(acc[2], u0.z); acc2(acc[3], u0.w);
        acc2(acc[0], u1.x); acc2(acc[1], u1.y); acc2(acc[2], u1.z); acc2(acc[3], u1.w);
        acc2(acc[0], u2.x); acc2(acc[1], u2.y); acc2(acc[2], u2.z); acc2(acc[3], u2.w);
        acc2(acc[0], u3.x); acc2(acc[1], u3.y); acc2(acc[2], u3.z); acc2(acc[3], u3.w);
    }
    for (; e + 2 <= end; e += 2) {
        int j = col[e + slot];
        uint4 u = h4[(size_t)j * 32 + c8];
        acc2(acc[0], u.x); acc2(acc[1], u.y); acc2(acc[2], u.z); acc2(acc[3], u.w);
    }
    if (e < end && slot == 0) {
        int j = col[e];
        uint4 u = h4[(size_t)j * 32 + c8];
        acc2(acc[0], u.x); acc2(acc[1], u.y); acc2(acc[2], u.z); acc2(acc[3], u.w);
    }
#pragma unroll
    for (int k = 0; k < 4; ++k) {
        acc[k].x += __shfl_xor(acc[k].x, 32);
        acc[k].y += __shfl_xor(acc[k].y, 32);
    }
    if (slot == 0) {
        float o0, o1; uint4 r;
        o0 = A[0].x * acc[0].x + B[0].x * degp1; o1 = A[0].y * acc[0].y + B[0].y * degp1;
        r.x = (uint32)f2bf(o0) | ((uint32)f2bf(o1) << 16);
        o0 = A[1].x * acc[1].x + B[1].x * degp1; o1 = A[1].y * acc[1].y + B[1].y * degp1;
        r.y = (uint32)f2bf(o0) | ((uint32)f2bf(o1) << 16);
        o0 = A[2].x * acc[2].x + B[2].x * degp1; o1 = A[2].y * acc[2].y + B[2].y * degp1;
        r.z = (uint32)f2bf(o0) | ((uint32)f2bf(o1) << 16);
        o0 = A[3].x * acc[3].x + B[3].x * degp1; o1 = A[3].y * acc[3].y + B[3].y * degp1;
        r.w = (uint32)f2bf(o0) | ((uint32)f2bf(o1) << 16);
        out[(size_t)gw * 32 + c8] = r;
    }
}

// ---------------- fused dual-branch MLP ----------------
// blockIdx.y = branch. Y(concat, stride 256, off br*128) = relu(relu(X@W1+b1)@W2+b2); BN stats.
__global__ __launch_bounds__(256, 2) void mlp_dual_kernel(
    const unsigned short* __restrict__ X, int in_stride, int in_off_mul,
    const unsigned short* __restrict__ wf_all,
    const float* __restrict__ b1a, const float* __restrict__ b1b,
    const float* __restrict__ b2a, const float* __restrict__ b2b,
    int l, unsigned short* __restrict__ Y, float* __restrict__ stats, int n) {
    __shared__ unsigned short w1s[MAT_STRIDE];     // 32 KB
    __shared__ unsigned short hs[4][16][136];      // 17.4 KB
    __shared__ float ssum[128], ssq[128];

    int br = blockIdx.y;
    const unsigned short* Wf = wf_all + (size_t)(br * 3 + l) * 2 * MAT_STRIDE;
    const float* b1 = (br ? b1b : b1a) + l * 128;
    const float* b2 = (br ? b2b : b2a) + l * 128;
    float* statsp = stats + (size_t)(l * 2 + br) * 256;
    int in_off = in_off_mul * br;

    int tid = threadIdx.x;
    int wv = tid >> 6, lane = tid & 63;
    int quad = lane >> 4, l16 = lane & 15;

    {
        const uint4* srcp = (const uint4*)Wf;
        uint4* dstp = (uint4*)w1s;
        for (int i = tid; i < 2048; i += 256) dstp[i] = srcp[i];
    }
    if (tid < 128) { ssum[tid] = 0.f; ssq[tid] = 0.f; }
    __syncthreads();

    bf16x8 w2f[8][4];
    {
        const bf16x8* w2g = (const bf16x8*)(Wf + MAT_STRIDE);
#pragma unroll
        for (int nt = 0; nt < 8; ++nt)
#pragma unroll
            for (int ks = 0; ks < 4; ++ks) w2f[nt][ks] = w2g[(nt * 4 + ks) * 64 + lane];
    }

    int row0 = blockIdx.x * 64 + wv * 16;

    bf16x8 aF[4];
    {
        int r = row0 + l16;
        if (r >= n) r = n - 1;
        const unsigned short* xrow = X + (size_t)r * in_stride + in_off;
#pragma unroll
        for (int ks = 0; ks < 4; ++ks) aF[ks] = *(const bf16x8*)(xrow + ks * 32 + quad * 8);
    }

    f32x4 acc1[8];
#pragma unroll
    for (int nt = 0; nt < 8; ++nt) {
        f32x4 c = {0.f, 0.f, 0.f, 0.f};
#pragma unroll
        for (int ks = 0; ks < 4; ++ks) {
            bf16x8 bfrag = *(const bf16x8*)(&w1s[((nt * 4 + ks) * 64 + lane) * 8]);
            c = __builtin_amdgcn_mfma_f32_16x16x32_bf16(aF[ks], bfrag, c, 0, 0, 0);
        }
        acc1[nt] = c;
    }

#pragma unroll
    for (int nt = 0; nt < 8; ++nt) {
        int c0 = nt * 16 + l16;
        float bb = b1[c0];
#pragma unroll
        for (int r = 0; r < 4; ++r) {
            float v = fmaxf(acc1[nt][r] + bb, 0.f);
            hs[wv][quad * 4 + r][c0] = f2bf(v);
        }
    }

    bf16x8 aH[4];
#pragma unroll
    for (int ks = 0; ks < 4; ++ks)
        aH[ks] = *(const bf16x8*)(&hs[wv][l16][ks * 32 + quad * 8]);

    f32x4 acc2_[8];
#pragma unroll
    for (int nt = 0; nt < 8; ++nt) {
        f32x4 c = {0.f, 0.f, 0.f, 0.f};
#pragma unroll
        for (int ks = 0; ks < 4; ++ks)
            c = __builtin_amdgcn_mfma_f32_16x16x32_bf16(aH[ks], w2f[nt][ks], c, 0, 0, 0);
        acc2_[nt] = c;
    }

#pragma unroll
    for (int nt = 0; nt < 8; ++nt) {
        int c0 = nt * 16 + l16;
        float bb = b2[c0];
        float s = 0.f, sq = 0.f;
#pragma unroll
        for (int r = 0; r < 4; ++r) {
            float v = fmaxf(acc2_[nt][r] + bb, 0.f);
            if (row0 + quad * 4 + r >= n) v = 0.f;
            s += v; sq += v * v;
            hs[wv][quad * 4 + r][c0] = f2bf(v);
        }
        s += __shfl_xor(s, 16); s += __shfl_xor(s, 32);
        sq += __shfl_xor(sq, 16); sq += __shfl_xor(sq, 32);
        if (quad == 0) { atomicAdd(&ssum[c0], s); atomicAdd(&ssq[c0], sq); }
    }

    {
        int grow = row0 + l16;
        if (grow < n) {
#pragma unroll
            for (int j = 0; j < 4; ++j) {
                uint4 v = *(const uint4*)(&hs[wv][l16][quad * 32 + j * 8]);
                *(uint4*)(Y + (size_t)grow * 256 + br * 128 + quad * 32 + j * 8) = v;
            }
        }
    }
    __syncthreads();
    if (tid < 128) {
        atomicAdd(&statsp[tid], ssum[tid]);
        atomicAdd(&statsp[128 + tid], ssq[tid]);
    }
}

// ---------------- dual pooling from concat buffer ----------------
#define POOL_CHUNK 128
__global__ void pool_dual_kernel(const unsigned short* __restrict__ h,
                                 const float* __restrict__ stats,
                                 const float* __restrict__ ga, const float* __restrict__ bta,
                                 const float* __restrict__ gb, const float* __restrict__ btb,
                                 const int* __restrict__ batch,
                                 float* __restrict__ poolA, float* __restrict__ poolB, int n) {
    int t = threadIdx.x;       // 256 threads: ch t of concat row
    int br = t >> 7, cc = t & 127;
    const float* st = stats + (size_t)(2 * 2 + br) * 256;   // layer 2 stats
    float s = st[cc], sq = st[128 + cc];
    float mu = s * (1.f / NN);
    float var = sq * (1.f / NN) - mu * mu;
    float gm = (br ? gb : ga)[2 * 128 + cc];
    float a = gm * rsqrtf(var + BN_EPS);
    float b = (br ? btb : bta)[2 * 128 + cc] - mu * a;
    float* pool = br ? poolB : poolA;

    int i0 = blockIdx.x * POOL_CHUNK;
    if (i0 >= n) return;
    int i1 = min(i0 + POOL_CHUNK, n);
    float acc = 0.f;
    int cur = batch[i0];
    for (int i = i0; i < i1; ++i) {
        int g = batch[i];
        if (g != cur) {
            atomicAdd(&pool[cur * 128 + cc], acc);
            acc = 0.f;
            cur = g;
        }
        acc += a * bf2f(h[(size_t)i * 256 + t]) + b;
    }
    atomicAdd(&pool[cur * 128 + cc], acc);
}

// ---------------- bilinear discriminator (mean inline) ----------------
__global__ void disc_kernel(const float* __restrict__ poolB, const float* __restrict__ cnt,
                            const float* __restrict__ W, const float* __restrict__ db,
                            float* __restrict__ out) {
    int g = blockIdx.x, e = threadIdx.x;    // 128 threads
    __shared__ float rs[128], rh[128];
    float invc = 1.f / fmaxf(cnt[g], 1.f);
    int gs = (g == 32) ? 30 : (63 - g);
    float invcs = 1.f / fmaxf(cnt[gs], 1.f);
    const float* a = poolB + g * 128;
    float t = 0.f;
    for (int d = 0; d < 128; ++d) t += a[d] * W[d * 128 + e];
    t *= invc;
    rs[e] = t * poolB[g * 128 + e] * invc;
    rh[e] = t * poolB[gs * 128 + e] * invcs;
    __syncthreads();
    for (int s = 64; s > 0; s >>= 1) {
        if (e < s) { rs[e] += rs[e + s]; rh[e] += rh[e + s]; }
        __syncthreads();
    }
    if (e == 0) {
        out[GG * 10 + g] = rs[0] + db[0];
        out[GG * 10 + GG + g] = rh[0] + db[0];
    }
}

// ---------------- classification head (mean inline) ----------------
__global__ void head_kernel(const float* __restrict__ poolA, const float* __restrict__ poolB,
                            const float* __restrict__ cnt,
                            const float* __restrict__ w1, const float* __restrict__ b1,
                            const float* __restrict__ w2, const float* __restrict__ b2,
                            float* __restrict__ out) {
    int g = blockIdx.x, j = threadIdx.x;   // 128 threads
    __shared__ float s1[128];
    __shared__ float s2[10];
    __shared__ float lse;
    float invc = 1.f / fmaxf(cnt[g], 1.f);
    const float* ma = poolA + g * 128;
    const float* px = poolB + g * 128;
    float acc = b1[j];
    for (int k = 0; k < 128; ++k) acc += ma[k] * invc * w1[k * 128 + j];
    for (int k = 0; k < 128; ++k) acc += px[k] * invc * w1[(128 + k) * 128 + j];
    s1[j] = fmaxf(acc, 0.f);
    __syncthreads();
    if (j < 10) {
        float a = b2[j];
        for (int k = 0; k < 128; ++k) a += s1[k] * w2[k * 10 + j];
        s2[j] = a;
    }
    __syncthreads();
    if (j == 0) {
        float m = s2[0];
        for (int o = 1; o < 10; ++o) m = fmaxf(m, s2[o]);
        float se = 0.f;
        for (int o = 0; o < 10; ++o) se += expf(s2[o] - m);
        lse = m + logf(se);
    }
    __syncthreads();
    if (j < 10) out[g * 10 + j] = s2[j] - lse;
}

extern "C" void kernel_launch(void* const* d_in, const int* in_sizes, int n_in,
                              void* d_out, int out_size, void* d_ws, size_t ws_size,
                              hipStream_t stream) {
    const float* x     = (const float*)d_in[0];
    const int*   ei    = (const int*)d_in[1];
    const int*   batch = (const int*)d_in[2];
    const float* W1a = (const float*)d_in[3];
    const float* b1a = (const float*)d_in[4];
    const float* W2a = (const float*)d_in[5];
    const float* b2a = (const float*)d_in[6];
    const float* ga  = (const float*)d_in[7];
    const float* bta = (const float*)d_in[8];
    const float* W1b = (const float*)d_in[9];
    const float* b1b = (const float*)d_in[10];
    const float* W2b = (const float*)d_in[11];
    const float* b2b = (const float*)d_in[12];
    const float* gb  = (const float*)d_in[13];
    const float* btb = (const float*)d_in[14];
    const float* lin1_w = (const float*)d_in[15];
    const float* lin1_b = (const float*)d_in[16];
    const float* lin2_w = (const float*)d_in[17];
    const float* lin2_b = (const float*)d_in[18];
    const float* disc_w = (const float*)d_in[19];
    const float* disc_b = (const float*)d_in[20];
    float* out = (float*)d_out;

    const int* src = ei;
    const int* dst = ei + EE;

    // ---- workspace layout ----
    size_t o = 0;
    auto take = [&](size_t b) { size_t p = o; o = (o + b + 255) & ~(size_t)255; return p; };
    uint8_t* w = (uint8_t*)d_ws;
    size_t o_xb   = take((size_t)NN * 128 * 2);   // bf16 x
    size_t o_g0   = take((size_t)NN * 128 * 2);   // shared layer-0 gather
    size_t o_bufP = take((size_t)NN * 256 * 2);   // concat layer outputs
    size_t o_gbuf = take((size_t)NN * 256 * 2);   // concat gathered
    size_t o_wf   = take((size_t)12 * MAT_STRIDE * 2);
    size_t o_col  = take((size_t)NBUCK * BCAP * 4);
    size_t o_part = take((size_t)NBUCK * BCAP * 4);
    size_t o_rowpair = take((size_t)NN * 8);
    size_t zero_begin = o;
    size_t o_bcnt   = take((size_t)NBUCK * 4);
    size_t o_stats  = take((size_t)6 * 256 * 4);
    size_t o_cnt    = take(GG * 4);
    size_t o_poolA  = take((size_t)GG * 128 * 4);
    size_t o_poolB  = take((size_t)GG * 128 * 4);
    size_t zero_end = o;

    uint32* xb = (uint32*)(w + o_xb);
    uint32* g0 = (uint32*)(w + o_g0);
    unsigned short* bufP = (unsigned short*)(w + o_bufP);
    unsigned short* gbuf = (unsigned short*)(w + o_gbuf);
    unsigned short* wf = (unsigned short*)(w + o_wf);
    int* col = (int*)(w + o_col);
    uint32* part = (uint32*)(w + o_part);
    int2* rowpair = (int2*)(w + o_rowpair);
    int* bcnt = (int*)(w + o_bcnt);
    float* stats = (float*)(w + o_stats);
    float* cnt = (float*)(w + o_cnt);
    float* poolA = (float*)(w + o_poolA);
    float* poolB = (float*)(w + o_poolB);

    hipMemsetAsync(w + zero_begin, 0, zero_end - zero_begin, stream);

    // conversions (independent of CSR)
    x_to_bf16_kernel<<<(NN * 32 + 255) / 256, 256, 0, stream>>>(x, xb);
    convert_w_kernel<<<(24576 + 255) / 256, 256, 0, stream>>>(W1a, W2a, W1b, W2b, wf);

    // CSR build (bucketed, no global scan)
    partition_kernel<<<(EE + PART_CHUNK - 1) / PART_CHUNK, 256, 0, stream>>>(src, dst, bcnt, part);
    build_col_kernel<<<NBUCK, 256, 0, stream>>>(part, bcnt, col, rowpair);
    counts_kernel<<<(NN + 255) / 256, 256, 0, stream>>>(batch, cnt, NN);

    int gatherBlocks = (NN + 3) / 4;   // 4 node-waves per block
    dim3 mlpGrid((NN + 63) / 64, 2);

    // shared layer-0 gather
    gather0_kernel<<<gatherBlocks, 256, 0, stream>>>((const uint4*)xb, rowpair, col, (uint4*)g0);

    // layer 0 (both branches read g0)
    mlp_dual_kernel<<<mlpGrid, 256, 0, stream>>>(
        (const unsigned short*)g0, 128, 0, wf, b1a, b1b, b2a, b2b, 0, bufP, stats, NN);
    // layers 1..2
    for (int l = 1; l < LL; ++l) {
        gather_dual_kernel<<<gatherBlocks, 256, 0, stream>>>(
            (const uint4*)bufP, rowpair, col, stats, ga, bta, gb, btb, l - 1, (uint4*)gbuf);
        mlp_dual_kernel<<<mlpGrid, 256, 0, stream>>>(
            gbuf, 256, 128, wf, b1a, b1b, b2a, b2b, l, bufP, stats, NN);
    }

    pool_dual_kernel<<<(NN + POOL_CHUNK - 1) / POOL_CHUNK, 256, 0, stream>>>(
        bufP, stats, ga, bta, gb, btb, batch, poolA, poolB, NN);
    disc_kernel<<<GG, 128, 0, stream>>>(poolB, cnt, disc_w, disc_b, out);
    head_kernel<<<GG, 128, 0, stream>>>(poolA, poolB, cnt, lin1_w, lin1_b, lin2_w, lin2_b, out);
}

// Round 5
// 849.771 us; speedup vs baseline: 2.6451x; 1.0027x over previous
//
#include <hip/hip_runtime.h>
#include <hip/hip_bf16.h>

#define NN 100000
#define EE 1600000
#define GG 64
#define HH 128
#define LL 3
#define BN_EPS 1e-5f
#define NBUCK 196          // ceil(NN/512)
#define BCAP 12288         // bucket capacity (mean 8163, +45 sigma safe)
#define PART_CHUNK 8192

typedef __attribute__((ext_vector_type(8))) short bf16x8;
typedef __attribute__((ext_vector_type(4))) float f32x4;
typedef unsigned int uint32;

__device__ __forceinline__ float bflo(uint32 u) { return __uint_as_float(u << 16); }
__device__ __forceinline__ float bfhi(uint32 u) { return __uint_as_float(u & 0xffff0000u); }
__device__ __forceinline__ unsigned short f2bf(float f) {
    uint32 x = __float_as_uint(f);
    uint32 r = (x + 0x7fffu + ((x >> 16) & 1u)) >> 16;
    return (unsigned short)r;
}
__device__ __forceinline__ float bf2f(unsigned short u) { return __uint_as_float(((uint32)u) << 16); }
__device__ __forceinline__ void acc2(float2& a, uint32 u) { a.x += bflo(u); a.y += bfhi(u); }

// ---------------- bucketed edge partition (fixed-capacity buckets) ----------------
// pack src (17 bits) | dst_local (9 bits) << 17
__global__ __launch_bounds__(256) void partition_kernel(
    const int* __restrict__ src, const int* __restrict__ dst,
    int* __restrict__ bcnt, uint32* __restrict__ part) {
    __shared__ int cnt[NBUCK];
    __shared__ int loff[NBUCK + 1];
    __shared__ int gpos[NBUCK];
    __shared__ int lcur[NBUCK];
    __shared__ uint32 buf[PART_CHUNK];
    int tid = threadIdx.x;
    int base = blockIdx.x * PART_CHUNK;
    int n = min(PART_CHUNK, EE - base);
    for (int i = tid; i < NBUCK; i += 256) { cnt[i] = 0; lcur[i] = 0; }
    __syncthreads();
    for (int i = tid; i < n; i += 256) atomicAdd(&cnt[dst[base + i] >> 9], 1);
    __syncthreads();
    if (tid == 0) {
        int acc = 0;
        for (int b = 0; b < NBUCK; ++b) { loff[b] = acc; acc += cnt[b]; }
        loff[NBUCK] = acc;
    }
    __syncthreads();
    if (tid < NBUCK && cnt[tid] > 0) gpos[tid] = atomicAdd(&bcnt[tid], cnt[tid]);
    __syncthreads();
    for (int i = tid; i < n; i += 256) {
        int d = dst[base + i];
        int s = src[base + i];
        int b = d >> 9;
        int slot = atomicAdd(&lcur[b], 1);
        buf[loff[b] + slot] = (uint32)s | ((uint32)(d & 511) << 17);
    }
    __syncthreads();
    for (int i = tid; i < n; i += 256) {
        int lo = 0, hi = NBUCK;
        while (hi - lo > 1) { int mid = (lo + hi) >> 1; if (loff[mid] <= i) lo = mid; else hi = mid; }
        part[(size_t)lo * BCAP + gpos[lo] + (i - loff[lo])] = buf[i];
    }
}

// ---------------- build per-bucket CSR + col (all in LDS) ----------------
__global__ __launch_bounds__(256) void build_col_kernel(
    const uint32* __restrict__ part, const int* __restrict__ bcnt,
    int* __restrict__ col, int2* __restrict__ rowpair) {
    __shared__ int ldeg[512];
    __shared__ int loffn[512];
    __shared__ int lcur[512];
    __shared__ int pscan[256];
    __shared__ int cl[BCAP];
    int b = blockIdx.x;
    int tid = threadIdx.x;
    int node0 = b << 9;
    int nn = min(node0 + 512, NN) - node0;
    int cnt = bcnt[b];
    int base = b * BCAP;
    const uint32* pp = part + (size_t)base;
    for (int i = tid; i < 512; i += 256) { ldeg[i] = 0; lcur[i] = 0; }
    __syncthreads();
    for (int i = tid; i < cnt; i += 256) atomicAdd(&ldeg[pp[i] >> 17], 1);
    __syncthreads();
    int t2 = tid * 2;
    int a0 = ldeg[t2], a1 = ldeg[t2 + 1];
    int ps = a0 + a1;
    pscan[tid] = ps;
    __syncthreads();
    for (int off = 1; off < 256; off <<= 1) {
        int v = (tid >= off) ? pscan[tid - off] : 0;
        __syncthreads();
        pscan[tid] += v;
        __syncthreads();
    }
    int eo = pscan[tid] - ps;       // exclusive over pairs
    loffn[t2] = eo;
    loffn[t2 + 1] = eo + a0;
    if (t2 < nn)     rowpair[node0 + t2]     = make_int2(base + eo, base + eo + a0);
    if (t2 + 1 < nn) rowpair[node0 + t2 + 1] = make_int2(base + eo + a0, base + eo + a0 + a1);
    __syncthreads();
    for (int i = tid; i < cnt; i += 256) {
        uint32 v = pp[i];
        int dl = (int)(v >> 17);
        int pos = atomicAdd(&lcur[dl], 1);
        cl[loffn[dl] + pos] = (int)(v & 0x1FFFFu);
    }
    __syncthreads();
    for (int i = tid; i < cnt; i += 256) col[base + i] = cl[i];
}

// ---------------- graph counts ----------------
__global__ void counts_kernel(const int* __restrict__ batch, float* __restrict__ cnt, int n) {
    __shared__ int h[GG];
    int tid = threadIdx.x;
    if (tid < GG) h[tid] = 0;
    __syncthreads();
    int i = blockIdx.x * 256 + tid;
    if (i < n) atomicAdd(&h[batch[i]], 1);
    __syncthreads();
    if (tid < GG && h[tid]) atomicAdd(&cnt[tid], (float)h[tid]);
}

// ---------------- conversions ----------------
__global__ void x_to_bf16_kernel(const float* __restrict__ x, uint32* __restrict__ xb) {
    int i = blockIdx.x * 256 + threadIdx.x;   // each handles 4 floats
    if (i < NN * 32) {
        float4 v = ((const float4*)x)[i];
        uint2 o;
        o.x = (uint32)f2bf(v.x) | ((uint32)f2bf(v.y) << 16);
        o.y = (uint32)f2bf(v.z) | ((uint32)f2bf(v.w) << 16);
        ((uint2*)xb)[i] = o;
    }
}

#define MAT_STRIDE 16384   // ushort elements per frag-ordered matrix

// frag-order weights: [br(2)][l(3)][mat(2)][nt(8)][ks(4)][lane(64)][j(8)]
__global__ void convert_w_kernel(const float* __restrict__ W1a, const float* __restrict__ W2a,
                                 const float* __restrict__ W1b, const float* __restrict__ W2b,
                                 unsigned short* __restrict__ out) {
    int t = blockIdx.x * 256 + threadIdx.x;
    if (t >= 24576) return;
    int lane = t & 63;
    int r = t >> 6;
    int ks = r & 3; r >>= 2;
    int nt = r & 7; r >>= 3;
    int mat = r & 1; r >>= 1;
    int l = r % 3, br = r / 3;
    const float* W = br ? (mat ? W2b : W1b) : (mat ? W2a : W1a);
    const float* Wl = W + (size_t)l * 128 * 128;
    int n0 = nt * 16 + (lane & 15);
    int k0 = ks * 32 + (lane >> 4) * 8;
    unsigned short tmp[8];
#pragma unroll
    for (int j = 0; j < 8; ++j) tmp[j] = f2bf(Wl[(size_t)(k0 + j) * 128 + n0]);
    size_t seq = (size_t)(br * 3 + l) * 2 + mat;
    size_t off = (((seq * 8 + nt) * 4 + ks) * 64 + (size_t)lane) * 8;
    *(uint4*)(out + off) = *(const uint4*)tmp;
}

// ---------------- layer-0 gather: g0[i] = bf16( x[i] + sum_j x[j] ), 128ch ----------------
// 4 edge-slots per wave, 16 lanes x uint4 (16B) per edge row (256 B)
__global__ void gather0_kernel(const uint4* __restrict__ h4, const int2* __restrict__ rowpair,
                               const int* __restrict__ col, uint4* __restrict__ out) {
    int gw = (blockIdx.x * blockDim.x + threadIdx.x) >> 6;
    int lane = threadIdx.x & 63;
    if (gw >= NN) return;
    int slot = lane >> 4;      // 0..3
    int c8 = lane & 15;        // channels 8*c8 .. +7
    float2 acc[4] = {{0.f,0.f},{0.f,0.f},{0.f,0.f},{0.f,0.f}};
    if (slot == 0) {
        uint4 s = h4[(size_t)gw * 16 + c8];
        acc2(acc[0], s.x); acc2(acc[1], s.y); acc2(acc[2], s.z); acc2(acc[3], s.w);
    }
    int2 be = rowpair[gw];
    int beg = be.x, end = be.y;
    int e = beg;
    for (; e + 8 <= end; e += 8) {
        int j0 = col[e + slot], j1 = col[e + 4 + slot];
        uint4 u0 = h4[(size_t)j0 * 16 + c8];
        uint4 u1 = h4[(size_t)j1 * 16 + c8];
        acc2(acc[0], u0.x); acc2(acc[1], u0.y); acc2(acc[2], u0.z); acc2(acc[3], u0.w);
        acc2(acc[0], u1.x); acc2(acc[1], u1.y); acc2(acc[2], u1.z); acc2(acc[3], u1.w);
    }
    for (; e + 4 <= end; e += 4) {
        int j = col[e + slot];
        uint4 u = h4[(size_t)j * 16 + c8];
        acc2(acc[0], u.x); acc2(acc[1], u.y); acc2(acc[2], u.z); acc2(acc[3], u.w);
    }
    int rem = end - e;
    if (slot < rem) {
        int j = col[e + slot];
        uint4 u = h4[(size_t)j * 16 + c8];
        acc2(acc[0], u.x); acc2(acc[1], u.y); acc2(acc[2], u.z); acc2(acc[3], u.w);
    }
#pragma unroll
    for (int k = 0; k < 4; ++k) {
        acc[k].x += __shfl_xor(acc[k].x, 16); acc[k].y += __shfl_xor(acc[k].y, 16);
        acc[k].x += __shfl_xor(acc[k].x, 32); acc[k].y += __shfl_xor(acc[k].y, 32);
    }
    if (slot == 0) {
        uint4 r;
        r.x = (uint32)f2bf(acc[0].x) | ((uint32)f2bf(acc[0].y) << 16);
        r.y = (uint32)f2bf(acc[1].x) | ((uint32)f2bf(acc[1].y) << 16);
        r.z = (uint32)f2bf(acc[2].x) | ((uint32)f2bf(acc[2].y) << 16);
        r.w = (uint32)f2bf(acc[3].x) | ((uint32)f2bf(acc[3].y) << 16);
        out[(size_t)gw * 16 + c8] = r;
    }
}

// ---------------- dual-branch gather on concat [N,256] rows ----------------
// full wave per edge: lane handles channels lane*4..+3 (uint2 = 8B); BN affine folded in.
__global__ void gather_dual_kernel(const uint2* __restrict__ h2, const int2* __restrict__ rowpair,
                                   const int* __restrict__ col, const float* __restrict__ stats,
                                   const float* __restrict__ ga, const float* __restrict__ bta,
                                   const float* __restrict__ gb, const float* __restrict__ btb,
                                   int lprev, uint2* __restrict__ out) {
    int gw = (blockIdx.x * blockDim.x + threadIdx.x) >> 6;
    int lane = threadIdx.x & 63;
    if (gw >= NN) return;
    int br = lane >> 5;
    const float* st = stats + (size_t)(lprev * 2 + br) * 256;
    const float* gmp = (br ? gb : ga) + lprev * 128;
    const float* btp = (br ? btb : bta) + lprev * 128;
    int cc0 = (lane * 4) & 127;
    float A[4], B[4];
#pragma unroll
    for (int j = 0; j < 4; ++j) {
        float s = st[cc0 + j], sq = st[128 + cc0 + j];
        float mu = s * (1.f / NN);
        float var = sq * (1.f / NN) - mu * mu;
        float a = gmp[cc0 + j] * rsqrtf(var + BN_EPS);
        A[j] = a;
        B[j] = btp[cc0 + j] - mu * a;
    }
    uint2 self = h2[(size_t)gw * 64 + lane];
    float p0 = bflo(self.x), p1 = bfhi(self.x), p2 = bflo(self.y), p3 = bfhi(self.y);
    float q0 = 0.f, q1 = 0.f, q2 = 0.f, q3 = 0.f;
    int2 be = rowpair[gw];
    int beg = be.x, end = be.y;
    float degp1 = (float)(end - beg + 1);
    int e = beg;
    for (; e + 4 <= end; e += 4) {
        uint2 u0 = h2[(size_t)col[e] * 64 + lane];
        uint2 u1 = h2[(size_t)col[e + 1] * 64 + lane];
        uint2 u2 = h2[(size_t)col[e + 2] * 64 + lane];
        uint2 u3 = h2[(size_t)col[e + 3] * 64 + lane];
        p0 += bflo(u0.x); p1 += bfhi(u0.x); p2 += bflo(u0.y); p3 += bfhi(u0.y);
        q0 += bflo(u1.x); q1 += bfhi(u1.x); q2 += bflo(u1.y); q3 += bfhi(u1.y);
        p0 += bflo(u2.x); p1 += bfhi(u2.x); p2 += bflo(u2.y); p3 += bfhi(u2.y);
        q0 += bflo(u3.x); q1 += bfhi(u3.x); q2 += bflo(u3.y); q3 += bfhi(u3.y);
    }
    for (; e < end; ++e) {
        uint2 u = h2[(size_t)col[e] * 64 + lane];
        p0 += bflo(u.x); p1 += bfhi(u.x); p2 += bflo(u.y); p3 += bfhi(u.y);
    }
    float o0 = A[0] * (p0 + q0) + B[0] * degp1;
    float o1 = A[1] * (p1 + q1) + B[1] * degp1;
    float o2 = A[2] * (p2 + q2) + B[2] * degp1;
    float o3 = A[3] * (p3 + q3) + B[3] * degp1;
    uint2 o;
    o.x = (uint32)f2bf(o0) | ((uint32)f2bf(o1) << 16);
    o.y = (uint32)f2bf(o2) | ((uint32)f2bf(o3) << 16);
    out[(size_t)gw * 64 + lane] = o;
}

// ---------------- fused dual-branch MLP ----------------
// blockIdx.y = branch. Y(concat, stride 256, off br*128) = relu(relu(X@W1+b1)@W2+b2); BN stats.
// W1 staged in LDS; W2 frags read directly from global (L2-broadcast) to cut VGPRs.
__global__ __launch_bounds__(256, 3) void mlp_dual_kernel(
    const unsigned short* __restrict__ X, int in_stride, int in_off_mul,
    const unsigned short* __restrict__ wf_all,
    const float* __restrict__ b1a, const float* __restrict__ b1b,
    const float* __restrict__ b2a, const float* __restrict__ b2b,
    int l, unsigned short* __restrict__ Y, float* __restrict__ stats, int n) {
    __shared__ unsigned short w1s[MAT_STRIDE];     // 32 KB
    __shared__ unsigned short hs[4][16][136];      // 17.4 KB
    __shared__ float ssum[128], ssq[128];

    int br = blockIdx.y;
    const unsigned short* Wf = wf_all + (size_t)(br * 3 + l) * 2 * MAT_STRIDE;
    const float* b1 = (br ? b1b : b1a) + l * 128;
    const float* b2 = (br ? b2b : b2a) + l * 128;
    float* statsp = stats + (size_t)(l * 2 + br) * 256;
    int in_off = in_off_mul * br;

    int tid = threadIdx.x;
    int wv = tid >> 6, lane = tid & 63;
    int quad = lane >> 4, l16 = lane & 15;

    {
        const uint4* srcp = (const uint4*)Wf;
        uint4* dstp = (uint4*)w1s;
        for (int i = tid; i < 2048; i += 256) dstp[i] = srcp[i];
    }
    if (tid < 128) { ssum[tid] = 0.f; ssq[tid] = 0.f; }
    __syncthreads();

    int row0 = blockIdx.x * 64 + wv * 16;

    bf16x8 aF[4];
    {
        int r = row0 + l16;
        if (r >= n) r = n - 1;
        const unsigned short* xrow = X + (size_t)r * in_stride + in_off;
#pragma unroll
        for (int ks = 0; ks < 4; ++ks) aF[ks] = *(const bf16x8*)(xrow + ks * 32 + quad * 8);
    }

    f32x4 acc1[8];
#pragma unroll
    for (int nt = 0; nt < 8; ++nt) {
        f32x4 c = {0.f, 0.f, 0.f, 0.f};
#pragma unroll
        for (int ks = 0; ks < 4; ++ks) {
            bf16x8 bfrag = *(const bf16x8*)(&w1s[((nt * 4 + ks) * 64 + lane) * 8]);
            c = __builtin_amdgcn_mfma_f32_16x16x32_bf16(aF[ks], bfrag, c, 0, 0, 0);
        }
        acc1[nt] = c;
    }

#pragma unroll
    for (int nt = 0; nt < 8; ++nt) {
        int c0 = nt * 16 + l16;
        float bb = b1[c0];
#pragma unroll
        for (int r = 0; r < 4; ++r) {
            float v = fmaxf(acc1[nt][r] + bb, 0.f);
            hs[wv][quad * 4 + r][c0] = f2bf(v);
        }
    }

    bf16x8 aH[4];
#pragma unroll
    for (int ks = 0; ks < 4; ++ks)
        aH[ks] = *(const bf16x8*)(&hs[wv][l16][ks * 32 + quad * 8]);

    const bf16x8* w2g = (const bf16x8*)(Wf + MAT_STRIDE);
    f32x4 acc2_[8];
#pragma unroll
    for (int nt = 0; nt < 8; ++nt) {
        bf16x8 bf0 = w2g[(nt * 4 + 0) * 64 + lane];
        bf16x8 bf1 = w2g[(nt * 4 + 1) * 64 + lane];
        bf16x8 bf2 = w2g[(nt * 4 + 2) * 64 + lane];
        bf16x8 bf3 = w2g[(nt * 4 + 3) * 64 + lane];
        f32x4 c = {0.f, 0.f, 0.f, 0.f};
        c = __builtin_amdgcn_mfma_f32_16x16x32_bf16(aH[0], bf0, c, 0, 0, 0);
        c = __builtin_amdgcn_mfma_f32_16x16x32_bf16(aH[1], bf1, c, 0, 0, 0);
        c = __builtin_amdgcn_mfma_f32_16x16x32_bf16(aH[2], bf2, c, 0, 0, 0);
        c = __builtin_amdgcn_mfma_f32_16x16x32_bf16(aH[3], bf3, c, 0, 0, 0);
        acc2_[nt] = c;
    }

#pragma unroll
    for (int nt = 0; nt < 8; ++nt) {
        int c0 = nt * 16 + l16;
        float bb = b2[c0];
        float s = 0.f, sq = 0.f;
#pragma unroll
        for (int r = 0; r < 4; ++r) {
            float v = fmaxf(acc2_[nt][r] + bb, 0.f);
            if (row0 + quad * 4 + r >= n) v = 0.f;
            s += v; sq += v * v;
            hs[wv][quad * 4 + r][c0] = f2bf(v);
        }
        s += __shfl_xor(s, 16); s += __shfl_xor(s, 32);
        sq += __shfl_xor(sq, 16); sq += __shfl_xor(sq, 32);
        if (quad == 0) { atomicAdd(&ssum[c0], s); atomicAdd(&ssq[c0], sq); }
    }

    {
        int grow = row0 + l16;
        if (grow < n) {
#pragma unroll
            for (int j = 0; j < 4; ++j) {
                uint4 v = *(const uint4*)(&hs[wv][l16][quad * 32 + j * 8]);
                *(uint4*)(Y + (size_t)grow * 256 + br * 128 + quad * 32 + j * 8) = v;
            }
        }
    }
    __syncthreads();
    if (tid < 128) {
        atomicAdd(&statsp[tid], ssum[tid]);
        atomicAdd(&statsp[128 + tid], ssq[tid]);
    }
}

// ---------------- dual pooling from concat buffer ----------------
#define POOL_CHUNK 128
__global__ void pool_dual_kernel(const unsigned short* __restrict__ h,
                                 const float* __restrict__ stats,
                                 const float* __restrict__ ga, const float* __restrict__ bta,
                                 const float* __restrict__ gb, const float* __restrict__ btb,
                                 const int* __restrict__ batch,
                                 float* __restrict__ poolA, float* __restrict__ poolB, int n) {
    int t = threadIdx.x;       // 256 threads: ch t of concat row
    int br = t >> 7, cc = t & 127;
    const float* st = stats + (size_t)(2 * 2 + br) * 256;   // layer 2 stats
    float s = st[cc], sq = st[128 + cc];
    float mu = s * (1.f / NN);
    float var = sq * (1.f / NN) - mu * mu;
    float gm = (br ? gb : ga)[2 * 128 + cc];
    float a = gm * rsqrtf(var + BN_EPS);
    float b = (br ? btb : bta)[2 * 128 + cc] - mu * a;
    float* pool = br ? poolB : poolA;

    int i0 = blockIdx.x * POOL_CHUNK;
    if (i0 >= n) return;
    int i1 = min(i0 + POOL_CHUNK, n);
    float acc = 0.f;
    int cur = batch[i0];
    for (int i = i0; i < i1; ++i) {
        int g = batch[i];
        if (g != cur) {
            atomicAdd(&pool[cur * 128 + cc], acc);
            acc = 0.f;
            cur = g;
        }
        acc += a * bf2f(h[(size_t)i * 256 + t]) + b;
    }
    atomicAdd(&pool[cur * 128 + cc], acc);
}

// ---------------- bilinear discriminator (mean inline) ----------------
__global__ void disc_kernel(const float* __restrict__ poolB, const float* __restrict__ cnt,
                            const float* __restrict__ W, const float* __restrict__ db,
                            float* __restrict__ out) {
    int g = blockIdx.x, e = threadIdx.x;    // 128 threads
    __shared__ float rs[128], rh[128];
    float invc = 1.f / fmaxf(cnt[g], 1.f);
    int gs = (g == 32) ? 30 : (63 - g);
    float invcs = 1.f / fmaxf(cnt[gs], 1.f);
    const float* a = poolB + g * 128;
    float t = 0.f;
    for (int d = 0; d < 128; ++d) t += a[d] * W[d * 128 + e];
    t *= invc;
    rs[e] = t * poolB[g * 128 + e] * invc;
    rh[e] = t * poolB[gs * 128 + e] * invcs;
    __syncthreads();
    for (int s = 64; s > 0; s >>= 1) {
        if (e < s) { rs[e] += rs[e + s]; rh[e] += rh[e + s]; }
        __syncthreads();
    }
    if (e == 0) {
        out[GG * 10 + g] = rs[0] + db[0];
        out[GG * 10 + GG + g] = rh[0] + db[0];
    }
}

// ---------------- classification head (mean inline) ----------------
__global__ void head_kernel(const float* __restrict__ poolA, const float* __restrict__ poolB,
                            const float* __restrict__ cnt,
                            const float* __restrict__ w1, const float* __restrict__ b1,
                            const float* __restrict__ w2, const float* __restrict__ b2,
                            float* __restrict__ out) {
    int g = blockIdx.x, j = threadIdx.x;   // 128 threads
    __shared__ float s1[128];
    __shared__ float s2[10];
    __shared__ float lse;
    float invc = 1.f / fmaxf(cnt[g], 1.f);
    const float* ma = poolA + g * 128;
    const float* px = poolB + g * 128;
    float acc = b1[j];
    for (int k = 0; k < 128; ++k) acc += ma[k] * invc * w1[k * 128 + j];
    for (int k = 0; k < 128; ++k) acc += px[k] * invc * w1[(128 + k) * 128 + j];
    s1[j] = fmaxf(acc, 0.f);
    __syncthreads();
    if (j < 10) {
        float a = b2[j];
        for (int k = 0; k < 128; ++k) a += s1[k] * w2[k * 10 + j];
        s2[j] = a;
    }
    __syncthreads();
    if (j == 0) {
        float m = s2[0];
        for (int o = 1; o < 10; ++o) m = fmaxf(m, s2[o]);
        float se = 0.f;
        for (int o = 0; o < 10; ++o) se += expf(s2[o] - m);
        lse = m + logf(se);
    }
    __syncthreads();
    if (j < 10) out[g * 10 + j] = s2[j] - lse;
}

extern "C" void kernel_launch(void* const* d_in, const int* in_sizes, int n_in,
                              void* d_out, int out_size, void* d_ws, size_t ws_size,
                              hipStream_t stream) {
    const float* x     = (const float*)d_in[0];
    const int*   ei    = (const int*)d_in[1];
    const int*   batch = (const int*)d_in[2];
    const float* W1a = (const float*)d_in[3];
    const float* b1a = (const float*)d_in[4];
    const float* W2a = (const float*)d_in[5];
    const float* b2a = (const float*)d_in[6];
    const float* ga  = (const float*)d_in[7];
    const float* bta = (const float*)d_in[8];
    const float* W1b = (const float*)d_in[9];
    const float* b1b = (const float*)d_in[10];
    const float* W2b = (const float*)d_in[11];
    const float* b2b = (const float*)d_in[12];
    const float* gb  = (const float*)d_in[13];
    const float* btb = (const float*)d_in[14];
    const float* lin1_w = (const float*)d_in[15];
    const float* lin1_b = (const float*)d_in[16];
    const float* lin2_w = (const float*)d_in[17];
    const float* lin2_b = (const float*)d_in[18];
    const float* disc_w = (const float*)d_in[19];
    const float* disc_b = (const float*)d_in[20];
    float* out = (float*)d_out;

    const int* src = ei;
    const int* dst = ei + EE;

    // ---- workspace layout ----
    size_t o = 0;
    auto take = [&](size_t b) { size_t p = o; o = (o + b + 255) & ~(size_t)255; return p; };
    uint8_t* w = (uint8_t*)d_ws;
    size_t o_xb   = take((size_t)NN * 128 * 2);   // bf16 x
    size_t o_g0   = take((size_t)NN * 128 * 2);   // shared layer-0 gather
    size_t o_bufP = take((size_t)NN * 256 * 2);   // concat layer outputs
    size_t o_gbuf = take((size_t)NN * 256 * 2);   // concat gathered
    size_t o_wf   = take((size_t)12 * MAT_STRIDE * 2);
    size_t o_col  = take((size_t)NBUCK * BCAP * 4);
    size_t o_part = take((size_t)NBUCK * BCAP * 4);
    size_t o_rowpair = take((size_t)NN * 8);
    size_t zero_begin = o;
    size_t o_bcnt   = take((size_t)NBUCK * 4);
    size_t o_stats  = take((size_t)6 * 256 * 4);
    size_t o_cnt    = take(GG * 4);
    size_t o_poolA  = take((size_t)GG * 128 * 4);
    size_t o_poolB  = take((size_t)GG * 128 * 4);
    size_t zero_end = o;

    uint32* xb = (uint32*)(w + o_xb);
    uint32* g0 = (uint32*)(w + o_g0);
    unsigned short* bufP = (unsigned short*)(w + o_bufP);
    unsigned short* gbuf = (unsigned short*)(w + o_gbuf);
    unsigned short* wf = (unsigned short*)(w + o_wf);
    int* col = (int*)(w + o_col);
    uint32* part = (uint32*)(w + o_part);
    int2* rowpair = (int2*)(w + o_rowpair);
    int* bcnt = (int*)(w + o_bcnt);
    float* stats = (float*)(w + o_stats);
    float* cnt = (float*)(w + o_cnt);
    float* poolA = (float*)(w + o_poolA);
    float* poolB = (float*)(w + o_poolB);

    hipMemsetAsync(w + zero_begin, 0, zero_end - zero_begin, stream);

    // conversions (independent of CSR)
    x_to_bf16_kernel<<<(NN * 32 + 255) / 256, 256, 0, stream>>>(x, xb);
    convert_w_kernel<<<(24576 + 255) / 256, 256, 0, stream>>>(W1a, W2a, W1b, W2b, wf);

    // CSR build (bucketed, no global scan)
    partition_kernel<<<(EE + PART_CHUNK - 1) / PART_CHUNK, 256, 0, stream>>>(src, dst, bcnt, part);
    build_col_kernel<<<NBUCK, 256, 0, stream>>>(part, bcnt, col, rowpair);
    counts_kernel<<<(NN + 255) / 256, 256, 0, stream>>>(batch, cnt, NN);

    int gatherBlocks = (NN + 3) / 4;   // 4 node-waves per block
    dim3 mlpGrid((NN + 63) / 64, 2);

    // shared layer-0 gather
    gather0_kernel<<<gatherBlocks, 256, 0, stream>>>((const uint4*)xb, rowpair, col, (uint4*)g0);

    // layer 0 (both branches read g0)
    mlp_dual_kernel<<<mlpGrid, 256, 0, stream>>>(
        (const unsigned short*)g0, 128, 0, wf, b1a, b1b, b2a, b2b, 0, bufP, stats, NN);
    // layers 1..2
    for (int l = 1; l < LL; ++l) {
        gather_dual_kernel<<<gatherBlocks, 256, 0, stream>>>(
            (const uint2*)bufP, rowpair, col, stats, ga, bta, gb, btb, l - 1, (uint2*)gbuf);
        mlp_dual_kernel<<<mlpGrid, 256, 0, stream>>>(
            gbuf, 256, 128, wf, b1a, b1b, b2a, b2b, l, bufP, stats, NN);
    }

    pool_dual_kernel<<<(NN + POOL_CHUNK - 1) / POOL_CHUNK, 256, 0, stream>>>(
        bufP, stats, ga, bta, gb, btb, batch, poolA, poolB, NN);
    disc_kernel<<<GG, 128, 0, stream>>>(poolB, cnt, disc_w, disc_b, out);
    head_kernel<<<GG, 128, 0, stream>>>(poolA, poolB, cnt, lin1_w, lin1_b, lin2_w, lin2_b, out);
}

// Round 6
// 758.451 us; speedup vs baseline: 2.9636x; 1.1204x over previous
//
#include <hip/hip_runtime.h>
#include <hip/hip_bf16.h>

#define NN 100000
#define EE 1600000
#define GG 64
#define HH 128
#define LL 3
#define BN_EPS 1e-5f
#define NBUCK 196          // ceil(NN/512)
#define BCAP 12288         // bucket capacity (mean 8163, +45 sigma safe)
#define PART_CHUNK 8192

typedef __attribute__((ext_vector_type(8))) short bf16x8;
typedef __attribute__((ext_vector_type(4))) float f32x4;
typedef unsigned int uint32;

__device__ __forceinline__ float bflo(uint32 u) { return __uint_as_float(u << 16); }
__device__ __forceinline__ float bfhi(uint32 u) { return __uint_as_float(u & 0xffff0000u); }
__device__ __forceinline__ unsigned short f2bf(float f) {
    uint32 x = __float_as_uint(f);
    uint32 r = (x + 0x7fffu + ((x >> 16) & 1u)) >> 16;
    return (unsigned short)r;
}
__device__ __forceinline__ float bf2f(unsigned short u) { return __uint_as_float(((uint32)u) << 16); }
__device__ __forceinline__ void acc2(float2& a, uint32 u) { a.x += bflo(u); a.y += bfhi(u); }
// dequant-accumulate 4 uint8 channels with per-row scale
__device__ __forceinline__ void accq(float4& a, uint32 u, float sc) {
    a.x += sc * (float)(u & 0xffu);
    a.y += sc * (float)((u >> 8) & 0xffu);
    a.z += sc * (float)((u >> 16) & 0xffu);
    a.w += sc * (float)(u >> 24);
}

// ---------------- bucketed edge partition (fixed-capacity buckets) ----------------
__global__ __launch_bounds__(256) void partition_kernel(
    const int* __restrict__ src, const int* __restrict__ dst,
    int* __restrict__ bcnt, uint32* __restrict__ part) {
    __shared__ int cnt[NBUCK];
    __shared__ int loff[NBUCK + 1];
    __shared__ int gpos[NBUCK];
    __shared__ int lcur[NBUCK];
    __shared__ uint32 buf[PART_CHUNK];
    int tid = threadIdx.x;
    int base = blockIdx.x * PART_CHUNK;
    int n = min(PART_CHUNK, EE - base);
    for (int i = tid; i < NBUCK; i += 256) { cnt[i] = 0; lcur[i] = 0; }
    __syncthreads();
    for (int i = tid; i < n; i += 256) atomicAdd(&cnt[dst[base + i] >> 9], 1);
    __syncthreads();
    if (tid == 0) {
        int acc = 0;
        for (int b = 0; b < NBUCK; ++b) { loff[b] = acc; acc += cnt[b]; }
        loff[NBUCK] = acc;
    }
    __syncthreads();
    if (tid < NBUCK && cnt[tid] > 0) gpos[tid] = atomicAdd(&bcnt[tid], cnt[tid]);
    __syncthreads();
    for (int i = tid; i < n; i += 256) {
        int d = dst[base + i];
        int s = src[base + i];
        int b = d >> 9;
        int slot = atomicAdd(&lcur[b], 1);
        buf[loff[b] + slot] = (uint32)s | ((uint32)(d & 511) << 17);
    }
    __syncthreads();
    for (int i = tid; i < n; i += 256) {
        int lo = 0, hi = NBUCK;
        while (hi - lo > 1) { int mid = (lo + hi) >> 1; if (loff[mid] <= i) lo = mid; else hi = mid; }
        part[(size_t)lo * BCAP + gpos[lo] + (i - loff[lo])] = buf[i];
    }
}

// ---------------- build per-bucket CSR + col (all in LDS) ----------------
__global__ __launch_bounds__(256) void build_col_kernel(
    const uint32* __restrict__ part, const int* __restrict__ bcnt,
    int* __restrict__ col, int2* __restrict__ rowpair) {
    __shared__ int ldeg[512];
    __shared__ int loffn[512];
    __shared__ int lcur[512];
    __shared__ int pscan[256];
    __shared__ int cl[BCAP];
    int b = blockIdx.x;
    int tid = threadIdx.x;
    int node0 = b << 9;
    int nn = min(node0 + 512, NN) - node0;
    int cnt = bcnt[b];
    int base = b * BCAP;
    const uint32* pp = part + (size_t)base;
    for (int i = tid; i < 512; i += 256) { ldeg[i] = 0; lcur[i] = 0; }
    __syncthreads();
    for (int i = tid; i < cnt; i += 256) atomicAdd(&ldeg[pp[i] >> 17], 1);
    __syncthreads();
    int t2 = tid * 2;
    int a0 = ldeg[t2], a1 = ldeg[t2 + 1];
    int ps = a0 + a1;
    pscan[tid] = ps;
    __syncthreads();
    for (int off = 1; off < 256; off <<= 1) {
        int v = (tid >= off) ? pscan[tid - off] : 0;
        __syncthreads();
        pscan[tid] += v;
        __syncthreads();
    }
    int eo = pscan[tid] - ps;       // exclusive over pairs
    loffn[t2] = eo;
    loffn[t2 + 1] = eo + a0;
    if (t2 < nn)     rowpair[node0 + t2]     = make_int2(base + eo, base + eo + a0);
    if (t2 + 1 < nn) rowpair[node0 + t2 + 1] = make_int2(base + eo + a0, base + eo + a0 + a1);
    __syncthreads();
    for (int i = tid; i < cnt; i += 256) {
        uint32 v = pp[i];
        int dl = (int)(v >> 17);
        int pos = atomicAdd(&lcur[dl], 1);
        cl[loffn[dl] + pos] = (int)(v & 0x1FFFFu);
    }
    __syncthreads();
    for (int i = tid; i < cnt; i += 256) col[base + i] = cl[i];
}

// ---------------- graph counts ----------------
__global__ void counts_kernel(const int* __restrict__ batch, float* __restrict__ cnt, int n) {
    __shared__ int h[GG];
    int tid = threadIdx.x;
    if (tid < GG) h[tid] = 0;
    __syncthreads();
    int i = blockIdx.x * 256 + tid;
    if (i < n) atomicAdd(&h[batch[i]], 1);
    __syncthreads();
    if (tid < GG && h[tid]) atomicAdd(&cnt[tid], (float)h[tid]);
}

// ---------------- conversions ----------------
__global__ void x_to_bf16_kernel(const float* __restrict__ x, uint32* __restrict__ xb) {
    int i = blockIdx.x * 256 + threadIdx.x;   // each handles 4 floats
    if (i < NN * 32) {
        float4 v = ((const float4*)x)[i];
        uint2 o;
        o.x = (uint32)f2bf(v.x) | ((uint32)f2bf(v.y) << 16);
        o.y = (uint32)f2bf(v.z) | ((uint32)f2bf(v.w) << 16);
        ((uint2*)xb)[i] = o;
    }
}

#define MAT_STRIDE 16384   // ushort elements per frag-ordered matrix

// frag-order weights: [br(2)][l(3)][mat(2)][nt(8)][ks(4)][lane(64)][j(8)]
__global__ void convert_w_kernel(const float* __restrict__ W1a, const float* __restrict__ W2a,
                                 const float* __restrict__ W1b, const float* __restrict__ W2b,
                                 unsigned short* __restrict__ out) {
    int t = blockIdx.x * 256 + threadIdx.x;
    if (t >= 24576) return;
    int lane = t & 63;
    int r = t >> 6;
    int ks = r & 3; r >>= 2;
    int nt = r & 7; r >>= 3;
    int mat = r & 1; r >>= 1;
    int l = r % 3, br = r / 3;
    const float* W = br ? (mat ? W2b : W1b) : (mat ? W2a : W1a);
    const float* Wl = W + (size_t)l * 128 * 128;
    int n0 = nt * 16 + (lane & 15);
    int k0 = ks * 32 + (lane >> 4) * 8;
    unsigned short tmp[8];
#pragma unroll
    for (int j = 0; j < 8; ++j) tmp[j] = f2bf(Wl[(size_t)(k0 + j) * 128 + n0]);
    size_t seq = (size_t)(br * 3 + l) * 2 + mat;
    size_t off = (((seq * 8 + nt) * 4 + ks) * 64 + (size_t)lane) * 8;
    *(uint4*)(out + off) = *(const uint4*)tmp;
}

// ---------------- layer-0 gather: g0[i] = bf16( x[i] + sum_j x[j] ), 128ch ----------------
__global__ void gather0_kernel(const uint4* __restrict__ h4, const int2* __restrict__ rowpair,
                               const int* __restrict__ col, uint4* __restrict__ out) {
    int gw = (blockIdx.x * blockDim.x + threadIdx.x) >> 6;
    int lane = threadIdx.x & 63;
    if (gw >= NN) return;
    int slot = lane >> 4;      // 0..3
    int c8 = lane & 15;        // channels 8*c8 .. +7
    float2 acc[4] = {{0.f,0.f},{0.f,0.f},{0.f,0.f},{0.f,0.f}};
    if (slot == 0) {
        uint4 s = h4[(size_t)gw * 16 + c8];
        acc2(acc[0], s.x); acc2(acc[1], s.y); acc2(acc[2], s.z); acc2(acc[3], s.w);
    }
    int2 be = rowpair[gw];
    int beg = be.x, end = be.y;
    int e = beg;
    for (; e + 8 <= end; e += 8) {
        int j0 = col[e + slot], j1 = col[e + 4 + slot];
        uint4 u0 = h4[(size_t)j0 * 16 + c8];
        uint4 u1 = h4[(size_t)j1 * 16 + c8];
        acc2(acc[0], u0.x); acc2(acc[1], u0.y); acc2(acc[2], u0.z); acc2(acc[3], u0.w);
        acc2(acc[0], u1.x); acc2(acc[1], u1.y); acc2(acc[2], u1.z); acc2(acc[3], u1.w);
    }
    for (; e + 4 <= end; e += 4) {
        int j = col[e + slot];
        uint4 u = h4[(size_t)j * 16 + c8];
        acc2(acc[0], u.x); acc2(acc[1], u.y); acc2(acc[2], u.z); acc2(acc[3], u.w);
    }
    int rem = end - e;
    if (slot < rem) {
        int j = col[e + slot];
        uint4 u = h4[(size_t)j * 16 + c8];
        acc2(acc[0], u.x); acc2(acc[1], u.y); acc2(acc[2], u.z); acc2(acc[3], u.w);
    }
#pragma unroll
    for (int k = 0; k < 4; ++k) {
        acc[k].x += __shfl_xor(acc[k].x, 16); acc[k].y += __shfl_xor(acc[k].y, 16);
        acc[k].x += __shfl_xor(acc[k].x, 32); acc[k].y += __shfl_xor(acc[k].y, 32);
    }
    if (slot == 0) {
        uint4 r;
        r.x = (uint32)f2bf(acc[0].x) | ((uint32)f2bf(acc[0].y) << 16);
        r.y = (uint32)f2bf(acc[1].x) | ((uint32)f2bf(acc[1].y) << 16);
        r.z = (uint32)f2bf(acc[2].x) | ((uint32)f2bf(acc[2].y) << 16);
        r.w = (uint32)f2bf(acc[3].x) | ((uint32)f2bf(acc[3].y) << 16);
        out[(size_t)gw * 16 + c8] = r;
    }
}

// ---------------- dual-branch gather on uint8 concat [N,256] rows + per-row scales ----------
// full wave per edge: lane handles channels lane*4..+3 (1 dword = 4 uint8 ch); BN affine folded.
__global__ void gather_dual_kernel(const uint32* __restrict__ y8, const float* __restrict__ scales,
                                   const int2* __restrict__ rowpair, const int* __restrict__ col,
                                   const float* __restrict__ stats,
                                   const float* __restrict__ ga, const float* __restrict__ bta,
                                   const float* __restrict__ gb, const float* __restrict__ btb,
                                   int lprev, uint2* __restrict__ out) {
    int gw = (blockIdx.x * blockDim.x + threadIdx.x) >> 6;
    int lane = threadIdx.x & 63;
    if (gw >= NN) return;
    int br = lane >> 5;
    const float* st = stats + (size_t)(lprev * 2 + br) * 256;
    const float* gmp = (br ? gb : ga) + lprev * 128;
    const float* btp = (br ? btb : bta) + lprev * 128;
    int cc0 = (lane * 4) & 127;
    float A[4], B[4];
#pragma unroll
    for (int j = 0; j < 4; ++j) {
        float s = st[cc0 + j], sq = st[128 + cc0 + j];
        float mu = s * (1.f / NN);
        float var = sq * (1.f / NN) - mu * mu;
        float a = gmp[cc0 + j] * rsqrtf(var + BN_EPS);
        A[j] = a;
        B[j] = btp[cc0 + j] - mu * a;
    }
    float4 accA = {0.f, 0.f, 0.f, 0.f};
    float4 accB = {0.f, 0.f, 0.f, 0.f};
    {   // self
        uint32 us = y8[(size_t)gw * 64 + lane];
        float ss = scales[gw * 2 + br];
        accq(accA, us, ss);
    }
    int2 be = rowpair[gw];
    int beg = be.x, end = be.y;
    float degp1 = (float)(end - beg + 1);
    int e = beg;
    for (; e + 4 <= end; e += 4) {
        int j0 = col[e], j1 = col[e + 1], j2 = col[e + 2], j3 = col[e + 3];
        uint32 u0 = y8[(size_t)j0 * 64 + lane]; float s0 = scales[j0 * 2 + br];
        uint32 u1 = y8[(size_t)j1 * 64 + lane]; float s1 = scales[j1 * 2 + br];
        uint32 u2 = y8[(size_t)j2 * 64 + lane]; float s2 = scales[j2 * 2 + br];
        uint32 u3 = y8[(size_t)j3 * 64 + lane]; float s3 = scales[j3 * 2 + br];
        accq(accA, u0, s0);
        accq(accB, u1, s1);
        accq(accA, u2, s2);
        accq(accB, u3, s3);
    }
    for (; e < end; ++e) {
        int j = col[e];
        uint32 u = y8[(size_t)j * 64 + lane];
        float s = scales[j * 2 + br];
        accq(accA, u, s);
    }
    float o0 = A[0] * (accA.x + accB.x) + B[0] * degp1;
    float o1 = A[1] * (accA.y + accB.y) + B[1] * degp1;
    float o2 = A[2] * (accA.z + accB.z) + B[2] * degp1;
    float o3 = A[3] * (accA.w + accB.w) + B[3] * degp1;
    uint2 o;
    o.x = (uint32)f2bf(o0) | ((uint32)f2bf(o1) << 16);
    o.y = (uint32)f2bf(o2) | ((uint32)f2bf(o3) << 16);
    out[(size_t)gw * 64 + lane] = o;
}

// ---------------- fused dual-branch MLP (128-row blocks, 2 tiles/wave) ----------------
// blockIdx.y = branch. quant=1: write uint8 rows + per-row scale. quant=0: bf16 concat rows.
__global__ __launch_bounds__(256, 2) void mlp_dual_kernel(
    const unsigned short* __restrict__ X, int in_stride, int in_off_mul,
    const unsigned short* __restrict__ wf_all,
    const float* __restrict__ b1a, const float* __restrict__ b1b,
    const float* __restrict__ b2a, const float* __restrict__ b2b,
    int l, int quant,
    unsigned short* __restrict__ Y, unsigned char* __restrict__ Y8,
    float* __restrict__ scales, float* __restrict__ stats, int n) {
    __shared__ unsigned short w1s[MAT_STRIDE];     // 32 KB
    __shared__ unsigned short hs[4][16][136];      // 17.4 KB (aliased as byte buf in quant epilogue)
    __shared__ float ssum[128], ssq[128];

    int br = blockIdx.y;
    const unsigned short* Wf = wf_all + (size_t)(br * 3 + l) * 2 * MAT_STRIDE;
    const float* b1 = (br ? b1b : b1a) + l * 128;
    const float* b2 = (br ? b2b : b2a) + l * 128;
    float* statsp = stats + (size_t)(l * 2 + br) * 256;
    int in_off = in_off_mul * br;

    int tid = threadIdx.x;
    int wv = tid >> 6, lane = tid & 63;
    int quad = lane >> 4, l16 = lane & 15;

    {
        const uint4* srcp = (const uint4*)Wf;
        uint4* dstp = (uint4*)w1s;
        for (int i = tid; i < 2048; i += 256) dstp[i] = srcp[i];
    }
    if (tid < 128) { ssum[tid] = 0.f; ssq[tid] = 0.f; }
    __syncthreads();

    const bf16x8* w2g = (const bf16x8*)(Wf + MAT_STRIDE);
    unsigned char* hs8 = (unsigned char*)&hs[wv][0][0];   // 16 rows x 144B stride

#pragma unroll
    for (int t = 0; t < 2; ++t) {
        int rowT = blockIdx.x * 128 + t * 64 + wv * 16;

        bf16x8 aF[4];
        {
            int r = rowT + l16;
            if (r >= n) r = n - 1;
            const unsigned short* xrow = X + (size_t)r * in_stride + in_off;
#pragma unroll
            for (int ks = 0; ks < 4; ++ks) aF[ks] = *(const bf16x8*)(xrow + ks * 32 + quad * 8);
        }

        f32x4 acc1[8];
#pragma unroll
        for (int nt = 0; nt < 8; ++nt) {
            f32x4 c = {0.f, 0.f, 0.f, 0.f};
#pragma unroll
            for (int ks = 0; ks < 4; ++ks) {
                bf16x8 bfrag = *(const bf16x8*)(&w1s[((nt * 4 + ks) * 64 + lane) * 8]);
                c = __builtin_amdgcn_mfma_f32_16x16x32_bf16(aF[ks], bfrag, c, 0, 0, 0);
            }
            acc1[nt] = c;
        }

#pragma unroll
        for (int nt = 0; nt < 8; ++nt) {
            int c0 = nt * 16 + l16;
            float bb = b1[c0];
#pragma unroll
            for (int r = 0; r < 4; ++r) {
                float v = fmaxf(acc1[nt][r] + bb, 0.f);
                hs[wv][quad * 4 + r][c0] = f2bf(v);
            }
        }

        bf16x8 aH[4];
#pragma unroll
        for (int ks = 0; ks < 4; ++ks)
            aH[ks] = *(const bf16x8*)(&hs[wv][l16][ks * 32 + quad * 8]);

        f32x4 acc2_[8];
#pragma unroll
        for (int nt = 0; nt < 8; ++nt) {
            bf16x8 bf0 = w2g[(nt * 4 + 0) * 64 + lane];
            bf16x8 bf1 = w2g[(nt * 4 + 1) * 64 + lane];
            bf16x8 bf2 = w2g[(nt * 4 + 2) * 64 + lane];
            bf16x8 bf3 = w2g[(nt * 4 + 3) * 64 + lane];
            f32x4 c = {0.f, 0.f, 0.f, 0.f};
            c = __builtin_amdgcn_mfma_f32_16x16x32_bf16(aH[0], bf0, c, 0, 0, 0);
            c = __builtin_amdgcn_mfma_f32_16x16x32_bf16(aH[1], bf1, c, 0, 0, 0);
            c = __builtin_amdgcn_mfma_f32_16x16x32_bf16(aH[2], bf2, c, 0, 0, 0);
            c = __builtin_amdgcn_mfma_f32_16x16x32_bf16(aH[3], bf3, c, 0, 0, 0);
            acc2_[nt] = c;
        }

        // bias2 + relu + OOB-zero + BN stats (in place)
#pragma unroll
        for (int nt = 0; nt < 8; ++nt) {
            int c0 = nt * 16 + l16;
            float bb = b2[c0];
            float s = 0.f, sq = 0.f;
#pragma unroll
            for (int r = 0; r < 4; ++r) {
                float v = fmaxf(acc2_[nt][r] + bb, 0.f);
                if (rowT + quad * 4 + r >= n) v = 0.f;
                acc2_[nt][r] = v;
                s += v; sq += v * v;
            }
            s += __shfl_xor(s, 16); s += __shfl_xor(s, 32);
            sq += __shfl_xor(sq, 16); sq += __shfl_xor(sq, 32);
            if (quad == 0) { atomicAdd(&ssum[c0], s); atomicAdd(&ssq[c0], sq); }
        }

        if (!quant) {
            // bf16 concat output (layer 2 -> pooling)
#pragma unroll
            for (int nt = 0; nt < 8; ++nt) {
                int c0 = nt * 16 + l16;
#pragma unroll
                for (int r = 0; r < 4; ++r) hs[wv][quad * 4 + r][c0] = f2bf(acc2_[nt][r]);
            }
            int grow = rowT + l16;
            if (grow < n) {
#pragma unroll
                for (int j = 0; j < 4; ++j) {
                    uint4 v = *(const uint4*)(&hs[wv][l16][quad * 32 + j * 8]);
                    *(uint4*)(Y + (size_t)grow * 256 + br * 128 + quad * 32 + j * 8) = v;
                }
            }
        } else {
            // uint8 row-quantized output (values >= 0 post-relu)
#pragma unroll
            for (int r = 0; r < 4; ++r) {
                float m = acc2_[0][r];
#pragma unroll
                for (int nt = 1; nt < 8; ++nt) m = fmaxf(m, acc2_[nt][r]);
                m = fmaxf(m, __shfl_xor(m, 1));
                m = fmaxf(m, __shfl_xor(m, 2));
                m = fmaxf(m, __shfl_xor(m, 4));
                m = fmaxf(m, __shfl_xor(m, 8));
                float sc = m * (1.f / 255.f);
                float inv = (m > 0.f) ? 255.f / m : 0.f;
                int grow = rowT + quad * 4 + r;
                if (l16 == r && grow < n) scales[grow * 2 + br] = sc;
#pragma unroll
                for (int nt = 0; nt < 8; ++nt) {
                    uint32 u = (uint32)__float2int_rn(acc2_[nt][r] * inv);
                    hs8[(quad * 4 + r) * 144 + nt * 16 + l16] = (unsigned char)u;
                }
            }
            int grow = rowT + l16;
            if (grow < n) {
                *(uint4*)(Y8 + (size_t)grow * 256 + br * 128 + quad * 32) =
                    *(const uint4*)(hs8 + l16 * 144 + quad * 32);
                *(uint4*)(Y8 + (size_t)grow * 256 + br * 128 + quad * 32 + 16) =
                    *(const uint4*)(hs8 + l16 * 144 + quad * 32 + 16);
            }
        }
    }
    __syncthreads();
    if (tid < 128) {
        atomicAdd(&statsp[tid], ssum[tid]);
        atomicAdd(&statsp[128 + tid], ssq[tid]);
    }
}

// ---------------- dual pooling from concat buffer ----------------
#define POOL_CHUNK 128
__global__ void pool_dual_kernel(const unsigned short* __restrict__ h,
                                 const float* __restrict__ stats,
                                 const float* __restrict__ ga, const float* __restrict__ bta,
                                 const float* __restrict__ gb, const float* __restrict__ btb,
                                 const int* __restrict__ batch,
                                 float* __restrict__ poolA, float* __restrict__ poolB, int n) {
    int t = threadIdx.x;       // 256 threads: ch t of concat row
    int br = t >> 7, cc = t & 127;
    const float* st = stats + (size_t)(2 * 2 + br) * 256;   // layer 2 stats
    float s = st[cc], sq = st[128 + cc];
    float mu = s * (1.f / NN);
    float var = sq * (1.f / NN) - mu * mu;
    float gm = (br ? gb : ga)[2 * 128 + cc];
    float a = gm * rsqrtf(var + BN_EPS);
    float b = (br ? btb : bta)[2 * 128 + cc] - mu * a;
    float* pool = br ? poolB : poolA;

    int i0 = blockIdx.x * POOL_CHUNK;
    if (i0 >= n) return;
    int i1 = min(i0 + POOL_CHUNK, n);
    float acc = 0.f;
    int cur = batch[i0];
    for (int i = i0; i < i1; ++i) {
        int g = batch[i];
        if (g != cur) {
            atomicAdd(&pool[cur * 128 + cc], acc);
            acc = 0.f;
            cur = g;
        }
        acc += a * bf2f(h[(size_t)i * 256 + t]) + b;
    }
    atomicAdd(&pool[cur * 128 + cc], acc);
}

// ---------------- bilinear discriminator (mean inline) ----------------
__global__ void disc_kernel(const float* __restrict__ poolB, const float* __restrict__ cnt,
                            const float* __restrict__ W, const float* __restrict__ db,
                            float* __restrict__ out) {
    int g = blockIdx.x, e = threadIdx.x;    // 128 threads
    __shared__ float rs[128], rh[128];
    float invc = 1.f / fmaxf(cnt[g], 1.f);
    int gs = (g == 32) ? 30 : (63 - g);
    float invcs = 1.f / fmaxf(cnt[gs], 1.f);
    const float* a = poolB + g * 128;
    float t = 0.f;
    for (int d = 0; d < 128; ++d) t += a[d] * W[d * 128 + e];
    t *= invc;
    rs[e] = t * poolB[g * 128 + e] * invc;
    rh[e] = t * poolB[gs * 128 + e] * invcs;
    __syncthreads();
    for (int s = 64; s > 0; s >>= 1) {
        if (e < s) { rs[e] += rs[e + s]; rh[e] += rh[e + s]; }
        __syncthreads();
    }
    if (e == 0) {
        out[GG * 10 + g] = rs[0] + db[0];
        out[GG * 10 + GG + g] = rh[0] + db[0];
    }
}

// ---------------- classification head (mean inline) ----------------
__global__ void head_kernel(const float* __restrict__ poolA, const float* __restrict__ poolB,
                            const float* __restrict__ cnt,
                            const float* __restrict__ w1, const float* __restrict__ b1,
                            const float* __restrict__ w2, const float* __restrict__ b2,
                            float* __restrict__ out) {
    int g = blockIdx.x, j = threadIdx.x;   // 128 threads
    __shared__ float s1[128];
    __shared__ float s2[10];
    __shared__ float lse;
    float invc = 1.f / fmaxf(cnt[g], 1.f);
    const float* ma = poolA + g * 128;
    const float* px = poolB + g * 128;
    float acc = b1[j];
    for (int k = 0; k < 128; ++k) acc += ma[k] * invc * w1[k * 128 + j];
    for (int k = 0; k < 128; ++k) acc += px[k] * invc * w1[(128 + k) * 128 + j];
    s1[j] = fmaxf(acc, 0.f);
    __syncthreads();
    if (j < 10) {
        float a = b2[j];
        for (int k = 0; k < 128; ++k) a += s1[k] * w2[k * 10 + j];
        s2[j] = a;
    }
    __syncthreads();
    if (j == 0) {
        float m = s2[0];
        for (int o = 1; o < 10; ++o) m = fmaxf(m, s2[o]);
        float se = 0.f;
        for (int o = 0; o < 10; ++o) se += expf(s2[o] - m);
        lse = m + logf(se);
    }
    __syncthreads();
    if (j < 10) out[g * 10 + j] = s2[j] - lse;
}

extern "C" void kernel_launch(void* const* d_in, const int* in_sizes, int n_in,
                              void* d_out, int out_size, void* d_ws, size_t ws_size,
                              hipStream_t stream) {
    const float* x     = (const float*)d_in[0];
    const int*   ei    = (const int*)d_in[1];
    const int*   batch = (const int*)d_in[2];
    const float* W1a = (const float*)d_in[3];
    const float* b1a = (const float*)d_in[4];
    const float* W2a = (const float*)d_in[5];
    const float* b2a = (const float*)d_in[6];
    const float* ga  = (const float*)d_in[7];
    const float* bta = (const float*)d_in[8];
    const float* W1b = (const float*)d_in[9];
    const float* b1b = (const float*)d_in[10];
    const float* W2b = (const float*)d_in[11];
    const float* b2b = (const float*)d_in[12];
    const float* gb  = (const float*)d_in[13];
    const float* btb = (const float*)d_in[14];
    const float* lin1_w = (const float*)d_in[15];
    const float* lin1_b = (const float*)d_in[16];
    const float* lin2_w = (const float*)d_in[17];
    const float* lin2_b = (const float*)d_in[18];
    const float* disc_w = (const float*)d_in[19];
    const float* disc_b = (const float*)d_in[20];
    float* out = (float*)d_out;

    const int* src = ei;
    const int* dst = ei + EE;

    // ---- workspace layout ----
    size_t o = 0;
    auto take = [&](size_t b) { size_t p = o; o = (o + b + 255) & ~(size_t)255; return p; };
    uint8_t* w = (uint8_t*)d_ws;
    size_t o_xb   = take((size_t)NN * 128 * 2);   // bf16 x
    size_t o_g0   = take((size_t)NN * 128 * 2);   // shared layer-0 gather
    size_t o_bufP = take((size_t)NN * 256 * 2);   // concat layer-2 output (bf16)
    size_t o_gbuf = take((size_t)NN * 256 * 2);   // concat gathered (bf16)
    size_t o_y8   = take((size_t)NN * 256);       // uint8 quantized layer outputs
    size_t o_scal = take((size_t)NN * 2 * 4);     // per-row per-branch scales
    size_t o_wf   = take((size_t)12 * MAT_STRIDE * 2);
    size_t o_col  = take((size_t)NBUCK * BCAP * 4);
    size_t o_part = take((size_t)NBUCK * BCAP * 4);
    size_t o_rowpair = take((size_t)NN * 8);
    size_t zero_begin = o;
    size_t o_bcnt   = take((size_t)NBUCK * 4);
    size_t o_stats  = take((size_t)6 * 256 * 4);
    size_t o_cnt    = take(GG * 4);
    size_t o_poolA  = take((size_t)GG * 128 * 4);
    size_t o_poolB  = take((size_t)GG * 128 * 4);
    size_t zero_end = o;

    uint32* xb = (uint32*)(w + o_xb);
    uint32* g0 = (uint32*)(w + o_g0);
    unsigned short* bufP = (unsigned short*)(w + o_bufP);
    unsigned short* gbuf = (unsigned short*)(w + o_gbuf);
    unsigned char* y8 = (unsigned char*)(w + o_y8);
    float* scales = (float*)(w + o_scal);
    unsigned short* wf = (unsigned short*)(w + o_wf);
    int* col = (int*)(w + o_col);
    uint32* part = (uint32*)(w + o_part);
    int2* rowpair = (int2*)(w + o_rowpair);
    int* bcnt = (int*)(w + o_bcnt);
    float* stats = (float*)(w + o_stats);
    float* cnt = (float*)(w + o_cnt);
    float* poolA = (float*)(w + o_poolA);
    float* poolB = (float*)(w + o_poolB);

    hipMemsetAsync(w + zero_begin, 0, zero_end - zero_begin, stream);

    // conversions (independent of CSR)
    x_to_bf16_kernel<<<(NN * 32 + 255) / 256, 256, 0, stream>>>(x, xb);
    convert_w_kernel<<<(24576 + 255) / 256, 256, 0, stream>>>(W1a, W2a, W1b, W2b, wf);

    // CSR build (bucketed, no global scan)
    partition_kernel<<<(EE + PART_CHUNK - 1) / PART_CHUNK, 256, 0, stream>>>(src, dst, bcnt, part);
    build_col_kernel<<<NBUCK, 256, 0, stream>>>(part, bcnt, col, rowpair);
    counts_kernel<<<(NN + 255) / 256, 256, 0, stream>>>(batch, cnt, NN);

    int gatherBlocks = (NN + 3) / 4;   // 4 node-waves per block
    dim3 mlpGrid((NN + 127) / 128, 2);

    // shared layer-0 gather
    gather0_kernel<<<gatherBlocks, 256, 0, stream>>>((const uint4*)xb, rowpair, col, (uint4*)g0);

    // layer 0 (both branches read g0) -> uint8
    mlp_dual_kernel<<<mlpGrid, 256, 0, stream>>>(
        (const unsigned short*)g0, 128, 0, wf, b1a, b1b, b2a, b2b, 0, 1,
        nullptr, y8, scales, stats, NN);
    // layer 1
    gather_dual_kernel<<<gatherBlocks, 256, 0, stream>>>(
        (const uint32*)y8, scales, rowpair, col, stats, ga, bta, gb, btb, 0, (uint2*)gbuf);
    mlp_dual_kernel<<<mlpGrid, 256, 0, stream>>>(
        gbuf, 256, 128, wf, b1a, b1b, b2a, b2b, 1, 1,
        nullptr, y8, scales, stats, NN);
    // layer 2 (bf16 out for pooling)
    gather_dual_kernel<<<gatherBlocks, 256, 0, stream>>>(
        (const uint32*)y8, scales, rowpair, col, stats, ga, bta, gb, btb, 1, (uint2*)gbuf);
    mlp_dual_kernel<<<mlpGrid, 256, 0, stream>>>(
        gbuf, 256, 128, wf, b1a, b1b, b2a, b2b, 2, 0,
        bufP, nullptr, nullptr, stats, NN);

    pool_dual_kernel<<<(NN + POOL_CHUNK - 1) / POOL_CHUNK, 256, 0, stream>>>(
        bufP, stats, ga, bta, gb, btb, batch, poolA, poolB, NN);
    disc_kernel<<<GG, 128, 0, stream>>>(poolB, cnt, disc_w, disc_b, out);
    head_kernel<<<GG, 128, 0, stream>>>(poolA, poolB, cnt, lin1_w, lin1_b, lin2_w, lin2_b, out);
}